// Round 7
// baseline (277.178 us; speedup 1.0000x reference)
//
#include <hip/hip_runtime.h>
#include <hip/hip_bf16.h>

#define NN 20000
#define NP1 20001
#define DIM 256
#define NE 320000

#define NBKT 79        // buckets of 256 dst rows (last bucket = 32 rows)
#define BROWS 256
#define ACH 4096       // edges per phase-A chunk
#define ABLK 79        // ceil(NE/ACH)
#define STAGE_CAP 6144

typedef __attribute__((ext_vector_type(8))) short short8v;   // 8 bf16 = 4 VGPRs
typedef __attribute__((ext_vector_type(4))) float float4v;
typedef __attribute__((ext_vector_type(2))) float float2v;
typedef __attribute__((ext_vector_type(8))) unsigned short ushort8v;

typedef __attribute__((address_space(3))) void lds_vp;
typedef const __attribute__((address_space(1))) void gbl_vp;

__device__ __forceinline__ unsigned short f2bf(float f) {
    unsigned int u = __float_as_uint(f);
    u += 0x7fffu + ((u >> 16) & 1u);          // round-to-nearest-even
    return (unsigned short)(u >> 16);
}
__device__ __forceinline__ unsigned char f2fp8(float f) {
    return (unsigned char)(__builtin_amdgcn_cvt_pk_fp8_f32(f, f, 0, 0) & 0xff);
}

__device__ __forceinline__ int slot_to_rel(int s) { return (s == 3) ? 4 : s; }

// ---------------------------------------------------------------------------
// Fused setup: bucket partial hist (atomic-free, private slices) |
// x -> {bf16, fp8} | weight prep | zero the loss accumulator
// ---------------------------------------------------------------------------
#define HIST_BLOCKS (4 * ABLK)             // 316
#define CONV_BLOCKS 7500                   // 3*NN*DIM / (256*8)
#define PREP_BLOCKS 768                    // 3 * 256

__global__ __launch_bounds__(256) void setup_kernel(const float* __restrict__ x,
                                                    const int* __restrict__ edges,
                                                    const float* __restrict__ Wr1,
                                                    const float* __restrict__ br1,
                                                    const float* __restrict__ Wo1,
                                                    const float* __restrict__ Wr2,
                                                    const float* __restrict__ br2,
                                                    const float* __restrict__ Wo2,
                                                    int* __restrict__ part,       // [4][ABLK][NBKT]
                                                    unsigned short* __restrict__ xb,
                                                    unsigned char* __restrict__ xq,
                                                    unsigned short* __restrict__ BT,
                                                    float* __restrict__ biascat,
                                                    float* __restrict__ out) {
    int b = blockIdx.x;
    if (b < HIST_BLOCKS) {
        if (b == 0 && threadIdx.x == 0) out[0] = 0.f;   // loss accumulator
        int s = b / ABLK, a = b - s * ABLK;
        int k = slot_to_rel(s);
        __shared__ int cnt[NBKT];
        for (int t = threadIdx.x; t < NBKT; t += 256) cnt[t] = 0;
        __syncthreads();
        int e0 = a * ACH;
        #pragma unroll
        for (int j = 0; j < 16; ++j) {
            int e = e0 + j * 256 + threadIdx.x;
            if (e < NE) atomicAdd(&cnt[edges[k * 2 * NE + NE + e] >> 8], 1);
        }
        __syncthreads();
        for (int t = threadIdx.x; t < NBKT; t += 256)
            part[(s * ABLK + a) * NBKT + t] = cnt[t];
    } else if (b < HIST_BLOCKS + CONV_BLOCKS) {
        size_t i = ((size_t)(b - HIST_BLOCKS) * 256 + threadIdx.x) * 8;
        float4 v0 = *(const float4*)(x + i);
        float4 v1 = *(const float4*)(x + i + 4);
        if (i < 2 * (size_t)NN * DIM) {    // bf16 roots only needed for types 0,1
            ushort8v o;
            o[0] = f2bf(v0.x); o[1] = f2bf(v0.y); o[2] = f2bf(v0.z); o[3] = f2bf(v0.w);
            o[4] = f2bf(v1.x); o[5] = f2bf(v1.y); o[6] = f2bf(v1.z); o[7] = f2bf(v1.w);
            *(ushort8v*)(xb + i) = o;
        }
        unsigned int w0 = __builtin_amdgcn_cvt_pk_fp8_f32(v0.x, v0.y, 0, 0);
        w0 = __builtin_amdgcn_cvt_pk_fp8_f32(v0.z, v0.w, w0, 1);
        unsigned int w1 = __builtin_amdgcn_cvt_pk_fp8_f32(v1.x, v1.y, 0, 0);
        w1 = __builtin_amdgcn_cvt_pk_fp8_f32(v1.z, v1.w, w1, 1);
        *(uint2*)(xq + i) = make_uint2(w0, w1);
    } else {
        int pb = b - HIST_BLOCKS - CONV_BLOCKS;
        int g = pb >> 8, n = pb & 255;
        const float* Wr = (g == 2) ? Wr2 : Wr1;
        const float* Wo = (g == 2) ? Wo2 : Wo1;
        const float* br = (g == 2) ? br2 : br1;
        int ka = (g == 1) ? 1 : 0;
        int kb = (g == 1) ? 4 : 2;
        for (int c = 0; c < 3; ++c) {
            int k = c * 256 + threadIdx.x;
            float v;
            if (k < 256)      v = Wr[(size_t)ka * 65536 + k * 256 + n];
            else if (k < 512) v = Wr[(size_t)kb * 65536 + (k - 256) * 256 + n];
            else              v = Wo[(size_t)ka * 65536 + (k - 512) * 256 + n] +
                                  Wo[(size_t)kb * 65536 + (k - 512) * 256 + n];
            BT[(size_t)g * 768 * 256 + (size_t)n * 768 + k] = f2bf(v);
        }
        if (n == 0) biascat[g * DIM + threadIdx.x] =
            br[ka * DIM + threadIdx.x] + br[kb * DIM + threadIdx.x];
    }
}

// ---------------------------------------------------------------------------
// Phase A: bin edges bucket-major. Pairs are PACKED to 4B: (src<<15)|dst
// (both < 32768). Halves pairs HBM traffic and the LDS staging buffer.
// ---------------------------------------------------------------------------
__global__ __launch_bounds__(256) void binA_scatter_kernel(const int* __restrict__ edges,
                                                           const int* __restrict__ part,
                                                           unsigned int* __restrict__ pairs) {
    int s = blockIdx.y, a0 = blockIdx.x;
    int k = slot_to_rel(s);
    const int* P = part + (size_t)s * ABLK * NBKT;
    __shared__ int tot[NBKT], pre[NBKT], bstart[NBKT];
    __shared__ int scn[NBKT], cur[NBKT], gb[NBKT];
    __shared__ unsigned int st[ACH];               // 16 KB packed
    if (threadIdx.x < NBKT) {
        int t = threadIdx.x, s_tot = 0, s_pre = 0;
        for (int a = 0; a < ABLK; ++a) {
            int v = P[a * NBKT + t];
            s_tot += v; if (a < a0) s_pre += v;
        }
        tot[t] = s_tot; pre[t] = s_pre;
    }
    __syncthreads();
    if (threadIdx.x == 0) {
        int run = 0;
        for (int b = 0; b < NBKT; ++b) { bstart[b] = run; run += tot[b]; }
        run = 0;
        for (int b = 0; b < NBKT; ++b) { scn[b] = run; run += P[a0 * NBKT + b]; }
    }
    __syncthreads();
    if (threadIdx.x < NBKT) {
        int t = threadIdx.x;
        cur[t] = scn[t];
        gb[t] = bstart[t] + pre[t] - scn[t];
    }
    __syncthreads();
    int e0 = a0 * ACH;
    #pragma unroll
    for (int j = 0; j < 16; ++j) {
        int e = e0 + j * 256 + threadIdx.x;
        if (e < NE) {
            unsigned int src = edges[k * 2 * NE + e];
            unsigned int dst = edges[k * 2 * NE + NE + e];
            int slot = atomicAdd(&cur[dst >> 8], 1);
            st[slot] = (src << 15) | dst;
        }
    }
    __syncthreads();
    int nthis = NE - e0; if (nthis > ACH) nthis = ACH;
    for (int i = threadIdx.x; i < nthis; i += 256) {
        unsigned int p = st[i];
        pairs[(size_t)s * NE + gb[(p & 32767u) >> 8] + i] = p;
    }
}

// ---------------------------------------------------------------------------
// Phase B: per (bucket, slot) — packed pairs loaded into LDS ONCE (stgIn),
// counted + scattered from LDS (no second global read), coalesced esorted
// write. LDS ~51 KB -> 3 blocks/CU.
// ---------------------------------------------------------------------------
__global__ __launch_bounds__(256) void binB_kernel(const unsigned int* __restrict__ pairs,
                                                   const int* __restrict__ part,
                                                   int* __restrict__ row_start,
                                                   int* __restrict__ esorted) {
    int s = blockIdx.y, b = blockIdx.x;
    const int* P = part + (size_t)s * ABLK * NBKT;
    __shared__ int tot[NBKT], bstartS[NBKT + 1];
    if (threadIdx.x < NBKT) {
        int t = threadIdx.x, s_tot = 0;
        for (int a = 0; a < ABLK; ++a) s_tot += P[a * NBKT + t];
        tot[t] = s_tot;
    }
    __syncthreads();
    if (threadIdx.x == 0) {
        int run = 0;
        for (int j = 0; j < NBKT; ++j) { bstartS[j] = run; run += tot[j]; }
        bstartS[NBKT] = run;
    }
    __syncthreads();
    int base = bstartS[b], end = bstartS[b + 1];
    int n = end - base;
    int row0 = b * BROWS;
    int nrows = NN - row0; if (nrows > BROWS) nrows = BROWS;

    __shared__ int rcnt[BROWS];
    __shared__ int rcur[BROWS];
    __shared__ unsigned int stgIn[STAGE_CAP];      // 24 KB
    __shared__ int stg[STAGE_CAP];                 // 24 KB
    __shared__ int w4[4];
    rcnt[threadIdx.x] = 0;
    __syncthreads();
    if (n <= STAGE_CAP) {
        for (int i = threadIdx.x; i < n; i += 256) {
            unsigned int p = pairs[(size_t)s * NE + base + i];
            stgIn[i] = p;
            atomicAdd(&rcnt[p & 255u], 1);
        }
    } else {
        for (int i = threadIdx.x; i < n; i += 256)
            atomicAdd(&rcnt[pairs[(size_t)s * NE + base + i] & 255u], 1);
    }
    __syncthreads();
    int lane = threadIdx.x & 63, w = threadIdx.x >> 6;
    int v = rcnt[threadIdx.x];
    int x = v;
    #pragma unroll
    for (int off = 1; off < 64; off <<= 1) {
        int t = __shfl_up(x, off, 64);
        if (lane >= off) x += t;
    }
    if (lane == 63) w4[w] = x;
    __syncthreads();
    int woff = 0;
    for (int j = 0; j < w; ++j) woff += w4[j];
    int excl = x - v + woff;
    if (threadIdx.x < nrows) row_start[s * NP1 + row0 + threadIdx.x] = base + excl;
    if (b == NBKT - 1 && threadIdx.x == 0) row_start[s * NP1 + NN] = end;
    rcur[threadIdx.x] = excl;
    __syncthreads();

    if (n <= STAGE_CAP) {
        for (int i = threadIdx.x; i < n; i += 256) {
            unsigned int p = stgIn[i];
            int pos = atomicAdd(&rcur[p & 255u], 1);
            stg[pos] = (int)(p >> 15);
        }
        __syncthreads();
        for (int i = threadIdx.x; i < n; i += 256)
            esorted[(size_t)s * NE + base + i] = stg[i];
    } else {  // pathological fallback
        for (int i = threadIdx.x; i < n; i += 256) {
            unsigned int p = pairs[(size_t)s * NE + base + i];
            int pos = atomicAdd(&rcur[p & 255u], 1);
            esorted[(size_t)s * NE + base + pos] = (int)(p >> 15);
        }
    }
}

// ---------------------------------------------------------------------------
// fp8 aggregation v3: OCTET (8 lanes) per dst row, 8 rows per wave, 32 rows
// per block. Each lane owns 32 feature dims (32B) of its octet's row -> no
// cross-lane reduction AND 2x the independent row-streams per wave vs the
// quad variant (8 vs 4) -> doubled outstanding-gather MLP in the
// latency-bound gather loop. 4-edge unroll with next-iteration index
// prefetch. XCD swizzle: relation in LOW bits of blockIdx.x.
// ---------------------------------------------------------------------------
__device__ __forceinline__ void acc_row16(float2v* acc2, uint4 raw) {
    float2v f;
    f = __builtin_amdgcn_cvt_pk_f32_fp8(raw.x, 0); acc2[0] += f;
    f = __builtin_amdgcn_cvt_pk_f32_fp8(raw.x, 1); acc2[1] += f;
    f = __builtin_amdgcn_cvt_pk_f32_fp8(raw.y, 0); acc2[2] += f;
    f = __builtin_amdgcn_cvt_pk_f32_fp8(raw.y, 1); acc2[3] += f;
    f = __builtin_amdgcn_cvt_pk_f32_fp8(raw.z, 0); acc2[4] += f;
    f = __builtin_amdgcn_cvt_pk_f32_fp8(raw.z, 1); acc2[5] += f;
    f = __builtin_amdgcn_cvt_pk_f32_fp8(raw.w, 0); acc2[6] += f;
    f = __builtin_amdgcn_cvt_pk_f32_fp8(raw.w, 1); acc2[7] += f;
}

__device__ __forceinline__ void agg_row_oct(const unsigned char* __restrict__ feat,
                                            int b, int e, int c,
                                            const int* __restrict__ es,
                                            unsigned short* __restrict__ outp) {
    float2v acc2[16] = {};
    unsigned coff = (unsigned)c << 5;              // 32B per lane
    int i = b;
    int s0 = 0, s1 = 0, s2 = 0, s3 = 0;
    if (i + 3 < e) { s0 = es[i]; s1 = es[i + 1]; s2 = es[i + 2]; s3 = es[i + 3]; }
    while (i + 3 < e) {
        const unsigned char* p0 = feat + (((unsigned)s0 << 8) | coff);
        const unsigned char* p1 = feat + (((unsigned)s1 << 8) | coff);
        const unsigned char* p2 = feat + (((unsigned)s2 << 8) | coff);
        const unsigned char* p3 = feat + (((unsigned)s3 << 8) | coff);
        uint4 r0a = *(const uint4*)p0, r0b = *(const uint4*)(p0 + 16);
        uint4 r1a = *(const uint4*)p1, r1b = *(const uint4*)(p1 + 16);
        uint4 r2a = *(const uint4*)p2, r2b = *(const uint4*)(p2 + 16);
        uint4 r3a = *(const uint4*)p3, r3b = *(const uint4*)(p3 + 16);
        i += 4;
        if (i + 3 < e) { s0 = es[i]; s1 = es[i + 1]; s2 = es[i + 2]; s3 = es[i + 3]; }
        acc_row16(acc2, r0a); acc_row16(acc2 + 8, r0b);
        acc_row16(acc2, r1a); acc_row16(acc2 + 8, r1b);
        acc_row16(acc2, r2a); acc_row16(acc2 + 8, r2b);
        acc_row16(acc2, r3a); acc_row16(acc2 + 8, r3b);
    }
    for (; i < e; ++i) {
        const unsigned char* p = feat + (((unsigned)es[i] << 8) | coff);
        acc_row16(acc2, *(const uint4*)p);
        acc_row16(acc2 + 8, *(const uint4*)(p + 16));
    }
    #pragma unroll
    for (int g = 0; g < 2; ++g) {
        ushort8v o0, o1;
        #pragma unroll
        for (int j = 0; j < 4; ++j) {
            o0[2 * j] = f2bf(acc2[8 * g + j].x);     o0[2 * j + 1] = f2bf(acc2[8 * g + j].y);
            o1[2 * j] = f2bf(acc2[8 * g + 4 + j].x); o1[2 * j + 1] = f2bf(acc2[8 * g + 4 + j].y);
        }
        *(ushort8v*)(outp + g * 16) = o0;
        *(ushort8v*)(outp + g * 16 + 8) = o1;
    }
}

__global__ __launch_bounds__(256) void aggregate_l1_kernel(const unsigned char* __restrict__ xq,
                                                           const int* __restrict__ row_start,
                                                           const int* __restrict__ esorted,
                                                           unsigned short* __restrict__ aggbase) {
    int bl = blockIdx.x;
    int s = bl & 3;                                // relation in low bits -> XCD pinning
    int rowblk = bl >> 2;                          // 32 rows per block
    int srct = (s == 2) ? 1 : ((s == 3) ? 2 : 0);
    const unsigned char* feat = xq + (size_t)srct * NN * DIM;
    const int* rs = row_start + s * NP1;
    const int* es = esorted + s * NE;
    unsigned short* out = aggbase + (size_t)s * NN * DIM;
    int w = threadIdx.x >> 6, lane = threadIdx.x & 63;
    int oct = lane >> 3, c = lane & 7;
    int row = rowblk * 32 + w * 8 + oct;           // 20000 % 32 == 0: no bounds check
    agg_row_oct(feat, rs[row], rs[row + 1], c, es,
                out + (size_t)row * DIM + c * 32);
}

__global__ __launch_bounds__(256) void aggregate_l2_kernel(const unsigned char* __restrict__ h0q,
                                                           const unsigned char* __restrict__ h1q,
                                                           const int* __restrict__ row_start,
                                                           const int* __restrict__ esorted,
                                                           unsigned short* __restrict__ aggbase) {
    int bl = blockIdx.x;
    int qsel = bl & 1;                             // slot in low bit -> XCD pinning
    int rowblk = bl >> 1;
    int slot = qsel ? 2 : 0;
    const unsigned char* feat = qsel ? h1q : h0q;
    const int* rs = row_start + slot * NP1;
    const int* es = esorted + slot * NE;
    unsigned short* out = aggbase + (size_t)slot * NN * DIM;
    int w = threadIdx.x >> 6, lane = threadIdx.x & 63;
    int oct = lane >> 3, c = lane & 7;
    int row = rowblk * 32 + w * 8 + oct;
    agg_row_oct(feat, rs[row], rs[row + 1], c, es,
                out + (size_t)row * DIM + c * 32);
}

// ---------------------------------------------------------------------------
// MFMA bf16 GEMM (layer 1) — R4 template (best measured). T2 swizzle (128B
// rows, slot ^ (row&7), pre-swizzled global src, linear LDS dest) + 2-phase
// raw-barrier pipeline with separate __shared__ arrays.
// ---------------------------------------------------------------------------
struct GemmArgs {
    const unsigned short* A0[2];
    const unsigned short* A1[2];
    const unsigned short* A2[2];
    const unsigned short* BT[2];
    const float* bias[2];
    unsigned short* Cb[2];   // bf16 out
    unsigned char* Cq[2];    // fp8 shadow out
    int relu;
    int M;
};

#define PIPE_BAR() asm volatile("s_waitcnt vmcnt(0)\n\ts_barrier" ::: "memory")

__global__ __launch_bounds__(256) void gemm_mfma_lds_kernel(GemmArgs ga) {
    __shared__ unsigned short As0[64 * 64];     // 8 KB
    __shared__ unsigned short As1[64 * 64];     // 8 KB
    __shared__ unsigned short Bs0[128 * 64];    // 16 KB
    __shared__ unsigned short Bs1[128 * 64];    // 16 KB
    int z = blockIdx.z;
    const unsigned short* Asrc[3] = {ga.A0[z], ga.A1[z], ga.A2[z]};
    const unsigned short* BT = ga.BT[z];
    int M = ga.M;

    int tid = threadIdx.x;
    int wave = tid >> 6, lane = tid & 63;
    int wc = wave;                                 // 4 col-groups of 32
    int row0 = blockIdx.x * 64;
    int col0 = blockIdx.y * 128;
    int q = lane >> 4, r = lane & 15;

    // Staging geometry: 8 lanes cover one 128B row; 16B slot XOR (row&7).
    int lrow = tid >> 3;                           // 0..31 (row within 32-row chunk)
    int gswz = (tid & 7) ^ (lrow & 7);             // swizzled global 16B slot
    int ldsbase = (tid & ~63) * 8;                 // halfwords, wave-uniform

    int ra0 = row0 + lrow;      if (ra0 > M - 1) ra0 = M - 1;
    int ra1 = row0 + 32 + lrow; if (ra1 > M - 1) ra1 = M - 1;
    size_t aoff0 = (size_t)ra0 * DIM + gswz * 8;
    size_t aoff1 = (size_t)ra1 * DIM + gswz * 8;
    size_t boff0 = (size_t)(col0 + lrow)      * 768 + gswz * 8;
    size_t boff1 = (size_t)(col0 + 32 + lrow) * 768 + gswz * 8;
    size_t boff2 = (size_t)(col0 + 64 + lrow) * 768 + gswz * 8;
    size_t boff3 = (size_t)(col0 + 96 + lrow) * 768 + gswz * 8;

    auto STAGE = [&](int bf, int t) {
        unsigned short* As = bf ? As1 : As0;       // constant bf -> folds
        unsigned short* Bs = bf ? Bs1 : Bs0;
        int seg = t >> 2;
        size_t kl = (size_t)(t & 3) * 64;          // k offset within A (DIM=256)
        size_t kb = (size_t)t * 64;                // k offset within BT (768)
        const unsigned short* Ap = Asrc[seg];
        __builtin_amdgcn_global_load_lds((gbl_vp*)(Ap + aoff0 + kl), (lds_vp*)&As[ldsbase],        16, 0, 0);
        __builtin_amdgcn_global_load_lds((gbl_vp*)(Ap + aoff1 + kl), (lds_vp*)&As[2048 + ldsbase], 16, 0, 0);
        __builtin_amdgcn_global_load_lds((gbl_vp*)(BT + boff0 + kb), (lds_vp*)&Bs[ldsbase],        16, 0, 0);
        __builtin_amdgcn_global_load_lds((gbl_vp*)(BT + boff1 + kb), (lds_vp*)&Bs[2048 + ldsbase], 16, 0, 0);
        __builtin_amdgcn_global_load_lds((gbl_vp*)(BT + boff2 + kb), (lds_vp*)&Bs[4096 + ldsbase], 16, 0, 0);
        __builtin_amdgcn_global_load_lds((gbl_vp*)(BT + boff3 + kb), (lds_vp*)&Bs[6144 + ldsbase], 16, 0, 0);
    };

    // Read-side swizzled slot offsets (halfwords), per-lane constants.
    int r7 = r & 7;
    int soff0 = ((0 * 4 + q) ^ r7) * 8;            // p = 0 (k 0..31)
    int soff1 = ((1 * 4 + q) ^ r7) * 8;            // p = 1 (k 32..63)

    float4v acc[4][2] = {};
    auto COMPUTE = [&](int bf) {
        const unsigned short* As = bf ? As1 : As0;
        const unsigned short* Bs = bf ? Bs1 : Bs0;
        #pragma unroll
        for (int p = 0; p < 2; ++p) {
            int so = p ? soff1 : soff0;
            short8v a[4], b[2];
            #pragma unroll
            for (int i = 0; i < 4; ++i)
                a[i] = *(const short8v*)&As[(i * 16 + r) * 64 + so];
            #pragma unroll
            for (int j = 0; j < 2; ++j)
                b[j] = *(const short8v*)&Bs[(wc * 32 + j * 16 + r) * 64 + so];
            #pragma unroll
            for (int i = 0; i < 4; ++i)
                #pragma unroll
                for (int j = 0; j < 2; ++j)
                    acc[i][j] = __builtin_amdgcn_mfma_f32_16x16x32_bf16(a[i], b[j], acc[i][j], 0, 0, 0);
        }
    };

    // 12 K-steps of BK=64 (K = 768), 2-phase double buffer.
    STAGE(0, 0);
    PIPE_BAR();
    #pragma unroll 1
    for (int t = 0; t < 10; t += 2) {
        STAGE(1, t + 1);
        COMPUTE(0);
        PIPE_BAR();
        STAGE(0, t + 2);
        COMPUTE(1);
        PIPE_BAR();
    }
    STAGE(1, 11);
    COMPUTE(0);             // t = 10
    PIPE_BAR();
    COMPUTE(1);             // t = 11

    // Epilogue. C/D layout: col = r, row = q*4 + e
    unsigned short* Cb = ga.Cb[z];
    unsigned char* Cq = ga.Cq[z];
    int colW0 = col0 + wc * 32;
    float bj[2];
    #pragma unroll
    for (int j = 0; j < 2; ++j) bj[j] = ga.bias[z][colW0 + j * 16 + r];
    #pragma unroll
    for (int i = 0; i < 4; ++i) {
        int rowb = row0 + i * 16 + q * 4;
        #pragma unroll
        for (int e = 0; e < 4; ++e) {
            int rowc = rowb + e;
            if (rowc < M) {
                #pragma unroll
                for (int j = 0; j < 2; ++j) {
                    int col = colW0 + j * 16 + r;
                    float v = acc[i][j][e] + bj[j];
                    if (ga.relu) v = fmaxf(v, 0.f);
                    Cb[(size_t)rowc * DIM + col] = f2bf(v);
                    Cq[(size_t)rowc * DIM + col] = f2fp8(v);
                }
            }
        }
    }
}

// ---------------------------------------------------------------------------
// Fused layer-2 GEMM + loss + MEAN: 64-row x 256-col tiles, 313 blocks.
// In-phase XOR swizzle (slot q ^ (r&3), pre-swizzled global src); mean fused
// via one atomicAdd per block. (Unchanged from R6.)
// ---------------------------------------------------------------------------
__global__ __launch_bounds__(256) void gemm_loss_kernel(const unsigned short* __restrict__ A0,
                                                        const unsigned short* __restrict__ A1,
                                                        const unsigned short* __restrict__ A2,
                                                        const unsigned short* __restrict__ BT,
                                                        const float* __restrict__ bias,
                                                        const int* __restrict__ y,
                                                        float* __restrict__ out) {
    __shared__ unsigned short Atile[2][64 * 32];    // 4 KB each
    __shared__ unsigned short Btile[2][256 * 32];   // 16 KB each
    __shared__ float redm[64][4];
    __shared__ float reds[64][4];
    __shared__ float ylog[64];
    __shared__ int ylds[64];
    const unsigned short* Asrc[3] = {A0, A1, A2};

    int tid = threadIdx.x;
    int wave = tid >> 6, lane = tid & 63;
    int wc = wave;                      // 4 waves = 4 col blocks of 64
    int row0 = blockIdx.x * 64;
    int q = lane >> 4, r = lane & 15;

    if (tid < 64) {
        int rowg = row0 + tid;
        ylds[tid] = (rowg < NN) ? y[rowg] : -1;
    }

    // Staging: 4 lanes per 64B row; 16B slot XOR (row&3) on the global src.
    int arow = tid >> 2;
    int aslot = (tid & 3) ^ (arow & 3);            // pre-swizzled 16B slot
    int acol = aslot * 8;
    int ra = row0 + arow; if (ra > NN - 1) ra = NN - 1;
    size_t aoff = (size_t)ra * DIM + acol;
    size_t boff0 = (size_t)(arow) * 768 + acol;    // row&3 == arow&3 for all
    size_t boff1 = (size_t)(64 + arow) * 768 + acol;
    size_t boff2 = (size_t)(128 + arow) * 768 + acol;
    size_t boff3 = (size_t)(192 + arow) * 768 + acol;
    int ldsA = (tid & ~63) * 8;
    int ldsB = (tid & ~63) * 8;

    // Read-side swizzled slot (halfword offset), per-lane constant.
    int soff = (q ^ (r & 3)) * 8;

    float4v acc[4][4] = {};
    #pragma unroll 1
    for (int seg = 0; seg < 3; ++seg) {
        const unsigned short* Ap = Asrc[seg];
        #pragma unroll 1
        for (int kt2 = 0; kt2 < 4; ++kt2) {
            int kl = kt2 * 64;
            int kb = seg * 256 + kl;
            #pragma unroll
            for (int p = 0; p < 2; ++p) {
                __builtin_amdgcn_global_load_lds((gbl_vp*)(Ap + aoff + kl + p * 32),
                                                 (lds_vp*)&Atile[p][ldsA], 16, 0, 0);
                __builtin_amdgcn_global_load_lds((gbl_vp*)(BT + boff0 + kb + p * 32),
                                                 (lds_vp*)&Btile[p][ldsB], 16, 0, 0);
                __builtin_amdgcn_global_load_lds((gbl_vp*)(BT + boff1 + kb + p * 32),
                                                 (lds_vp*)&Btile[p][2048 + ldsB], 16, 0, 0);
                __builtin_amdgcn_global_load_lds((gbl_vp*)(BT + boff2 + kb + p * 32),
                                                 (lds_vp*)&Btile[p][4096 + ldsB], 16, 0, 0);
                __builtin_amdgcn_global_load_lds((gbl_vp*)(BT + boff3 + kb + p * 32),
                                                 (lds_vp*)&Btile[p][6144 + ldsB], 16, 0, 0);
            }
            __syncthreads();
            #pragma unroll
            for (int p = 0; p < 2; ++p) {
                short8v a[4], b[4];
                #pragma unroll
                for (int i = 0; i < 4; ++i)
                    a[i] = *(const short8v*)&Atile[p][(i * 16 + r) * 32 + soff];
                #pragma unroll
                for (int j = 0; j < 4; ++j)
                    b[j] = *(const short8v*)&Btile[p][(wc * 64 + j * 16 + r) * 32 + soff];
                #pragma unroll
                for (int i = 0; i < 4; ++i)
                    #pragma unroll
                    for (int j = 0; j < 4; ++j)
                        acc[i][j] = __builtin_amdgcn_mfma_f32_16x16x32_bf16(a[i], b[j], acc[i][j], 0, 0, 0);
            }
            __syncthreads();
        }
    }

    float bj[4];
    #pragma unroll
    for (int j = 0; j < 4; ++j) bj[j] = bias[wc * 64 + j * 16 + r];
    #pragma unroll
    for (int i = 0; i < 4; ++i) {
        #pragma unroll
        for (int e = 0; e < 4; ++e) {
            int row_local = i * 16 + q * 4 + e;    // 0..63
            int ycls = ylds[row_local];
            float v[4];
            float m = -3.4e38f;
            #pragma unroll
            for (int j = 0; j < 4; ++j) {
                v[j] = acc[i][j][e] + bj[j];
                m = fmaxf(m, v[j]);
                int col = wc * 64 + j * 16 + r;
                if (col == ycls) ylog[row_local] = v[j];
            }
            #pragma unroll
            for (int off = 1; off < 16; off <<= 1) m = fmaxf(m, __shfl_xor(m, off, 64));
            float s = __expf(v[0] - m) + __expf(v[1] - m) + __expf(v[2] - m) + __expf(v[3] - m);
            #pragma unroll
            for (int off = 1; off < 16; off <<= 1) s += __shfl_xor(s, off, 64);
            if (r == 0) { redm[row_local][wc] = m; reds[row_local][wc] = s; }
        }
    }
    __syncthreads();
    if (tid < 64) {                                // wave 0 only (uniform per wave)
        float nllv = 0.f;
        int rowg = row0 + tid;
        if (rowg < NN) {
            float m0 = redm[tid][0], m1 = redm[tid][1], m2 = redm[tid][2], m3 = redm[tid][3];
            float mm = fmaxf(fmaxf(m0, m1), fmaxf(m2, m3));
            float ss = reds[tid][0] * __expf(m0 - mm) + reds[tid][1] * __expf(m1 - mm) +
                       reds[tid][2] * __expf(m2 - mm) + reds[tid][3] * __expf(m3 - mm);
            nllv = (mm + __logf(ss) - ylog[tid]) * (1.0f / NN);
        }
        #pragma unroll
        for (int off = 32; off; off >>= 1) nllv += __shfl_xor(nllv, off, 64);
        if (tid == 0) atomicAdd(out, nllv);
    }
}

// ---------------------------------------------------------------------------
extern "C" void kernel_launch(void* const* d_in, const int* in_sizes, int n_in,
                              void* d_out, int out_size, void* d_ws, size_t ws_size,
                              hipStream_t stream) {
    const float* x    = (const float*)d_in[0];
    const int*   edges= (const int*)d_in[1];
    const int*   y    = (const int*)d_in[2];
    const float* Wr1  = (const float*)d_in[3];
    const float* br1  = (const float*)d_in[4];
    const float* Wo1  = (const float*)d_in[5];
    const float* Wr2  = (const float*)d_in[6];
    const float* br2  = (const float*)d_in[7];
    const float* Wo2  = (const float*)d_in[8];
    float* out = (float*)d_out;

    char* ws = (char*)d_ws;
    size_t off = 0;
    auto alloc = [&](size_t bytes) {
        char* p = ws + off;
        off += (bytes + 511) & ~size_t(511);
        return p;
    };
    int*   part          = (int*)alloc(4 * (size_t)ABLK * NBKT * sizeof(int));
    unsigned int* pairs  = (unsigned int*)alloc(4 * (size_t)NE * sizeof(unsigned int));
    int*   rowstart      = (int*)alloc(4 * NP1 * sizeof(int));
    int*   esorted       = (int*)alloc(4 * (size_t)NE * sizeof(int));
    unsigned short* BT      = (unsigned short*)alloc(3 * 768 * (size_t)DIM * 2);
    float*          biascat = (float*)         alloc(3 * DIM * sizeof(float));
    unsigned short* xb      = (unsigned short*)alloc(2 * (size_t)NN * DIM * 2);
    unsigned char*  xq      = (unsigned char*) alloc(3 * (size_t)NN * DIM);
    unsigned short* agg     = (unsigned short*)alloc(4 * (size_t)NN * DIM * 2);
    unsigned short* h0      = (unsigned short*)alloc((size_t)NN * DIM * 2);
    unsigned short* h1      = (unsigned short*)alloc((size_t)NN * DIM * 2);
    unsigned char*  h0q     = (unsigned char*) alloc((size_t)NN * DIM);
    unsigned char*  h1q     = (unsigned char*) alloc((size_t)NN * DIM);
    (void)in_sizes; (void)n_in; (void)out_size; (void)ws_size;

    const size_t ND = (size_t)NN * DIM;

    // 1. Fused setup (bucket partial hist | x->bf16/fp8 | weights | out=0)
    setup_kernel<<<dim3(HIST_BLOCKS + CONV_BLOCKS + PREP_BLOCKS), 256, 0, stream>>>(
        x, edges, Wr1, br1, Wo1, Wr2, br2, Wo2, part, xb, xq, BT, biascat, out);

    // 2. Bucket sort: bin (packed 4B pairs) -> per-bucket LDS-staged scatter
    binA_scatter_kernel<<<dim3(ABLK, 4), 256, 0, stream>>>(edges, part, pairs);
    binB_kernel<<<dim3(NBKT, 4), 256, 0, stream>>>(pairs, part, rowstart, esorted);

    // 3. Layer-1 aggregation: octet-per-row, 32 rows/block, relation-per-XCD
    aggregate_l1_kernel<<<dim3((NN / 32) * 4), 256, 0, stream>>>(xq, rowstart, esorted, agg);

    // 4. Layer-1 MFMA GEMMs: 64x128 tiles, T2 swizzle + 2-phase pipe (R4 best)
    {
        GemmArgs ga;
        ga.A0[0] = agg + 0 * ND; ga.A1[0] = agg + 2 * ND; ga.A2[0] = xb + 0 * ND;
        ga.A0[1] = agg + 1 * ND; ga.A1[1] = agg + 3 * ND; ga.A2[1] = xb + 1 * ND;
        ga.BT[0] = BT + 0 * 768 * DIM; ga.BT[1] = BT + 1 * 768 * DIM;
        ga.bias[0] = biascat + 0 * DIM; ga.bias[1] = biascat + 1 * DIM;
        ga.Cb[0] = h0; ga.Cb[1] = h1;
        ga.Cq[0] = h0q; ga.Cq[1] = h1q;
        ga.relu = 1; ga.M = NN;
        gemm_mfma_lds_kernel<<<dim3((NN + 63) / 64, 2, 2), 256, 0, stream>>>(ga);
    }

    // 5. Layer-2 aggregation: octet-per-row, slot-per-XCD
    aggregate_l2_kernel<<<dim3((NN / 32) * 2), 256, 0, stream>>>(h0q, h1q, rowstart, esorted, agg);

    // 6. Fused layer-2 GEMM + softmax/nll + mean (atomic accumulate into out)
    gemm_loss_kernel<<<dim3((NN + 63) / 64), 256, 0, stream>>>(
        agg + 0 * ND, agg + 2 * ND, h0, BT + 2 * 768 * DIM, biascat + 2 * DIM, y, out);
}

// Round 8
// 267.179 us; speedup vs baseline: 1.0374x; 1.0374x over previous
//
#include <hip/hip_runtime.h>
#include <hip/hip_bf16.h>

#define NN 20000
#define NP1 20001
#define DIM 256
#define NE 320000

#define NBKT 79        // buckets of 256 dst rows (last bucket = 32 rows)
#define BROWS 256
#define ACH 4096       // edges per phase-A chunk
#define ABLK 79        // ceil(NE/ACH)
#define STAGE_CAP 6144

typedef __attribute__((ext_vector_type(8))) short short8v;   // 8 bf16 = 4 VGPRs
typedef __attribute__((ext_vector_type(4))) float float4v;
typedef __attribute__((ext_vector_type(2))) float float2v;
typedef __attribute__((ext_vector_type(8))) unsigned short ushort8v;

typedef __attribute__((address_space(3))) void lds_vp;
typedef const __attribute__((address_space(1))) void gbl_vp;

__device__ __forceinline__ unsigned short f2bf(float f) {
    unsigned int u = __float_as_uint(f);
    u += 0x7fffu + ((u >> 16) & 1u);          // round-to-nearest-even
    return (unsigned short)(u >> 16);
}
__device__ __forceinline__ unsigned char f2fp8(float f) {
    return (unsigned char)(__builtin_amdgcn_cvt_pk_fp8_f32(f, f, 0, 0) & 0xff);
}

__device__ __forceinline__ int slot_to_rel(int s) { return (s == 3) ? 4 : s; }

// ---------------------------------------------------------------------------
// Fused setup: bucket partial hist (atomic-free, private slices) |
// x -> {bf16, fp8} | weight prep | zero the loss accumulator
// ---------------------------------------------------------------------------
#define HIST_BLOCKS (4 * ABLK)             // 316
#define CONV_BLOCKS 7500                   // 3*NN*DIM / (256*8)
#define PREP_BLOCKS 768                    // 3 * 256

__global__ __launch_bounds__(256) void setup_kernel(const float* __restrict__ x,
                                                    const int* __restrict__ edges,
                                                    const float* __restrict__ Wr1,
                                                    const float* __restrict__ br1,
                                                    const float* __restrict__ Wo1,
                                                    const float* __restrict__ Wr2,
                                                    const float* __restrict__ br2,
                                                    const float* __restrict__ Wo2,
                                                    int* __restrict__ part,       // [4][ABLK][NBKT]
                                                    unsigned short* __restrict__ xb,
                                                    unsigned char* __restrict__ xq,
                                                    unsigned short* __restrict__ BT,
                                                    float* __restrict__ biascat,
                                                    float* __restrict__ out) {
    int b = blockIdx.x;
    if (b < HIST_BLOCKS) {
        if (b == 0 && threadIdx.x == 0) out[0] = 0.f;   // loss accumulator
        int s = b / ABLK, a = b - s * ABLK;
        int k = slot_to_rel(s);
        __shared__ int cnt[NBKT];
        for (int t = threadIdx.x; t < NBKT; t += 256) cnt[t] = 0;
        __syncthreads();
        int e0 = a * ACH;
        #pragma unroll
        for (int j = 0; j < 16; ++j) {
            int e = e0 + j * 256 + threadIdx.x;
            if (e < NE) atomicAdd(&cnt[edges[k * 2 * NE + NE + e] >> 8], 1);
        }
        __syncthreads();
        for (int t = threadIdx.x; t < NBKT; t += 256)
            part[(s * ABLK + a) * NBKT + t] = cnt[t];
    } else if (b < HIST_BLOCKS + CONV_BLOCKS) {
        size_t i = ((size_t)(b - HIST_BLOCKS) * 256 + threadIdx.x) * 8;
        float4 v0 = *(const float4*)(x + i);
        float4 v1 = *(const float4*)(x + i + 4);
        if (i < 2 * (size_t)NN * DIM) {    // bf16 roots only needed for types 0,1
            ushort8v o;
            o[0] = f2bf(v0.x); o[1] = f2bf(v0.y); o[2] = f2bf(v0.z); o[3] = f2bf(v0.w);
            o[4] = f2bf(v1.x); o[5] = f2bf(v1.y); o[6] = f2bf(v1.z); o[7] = f2bf(v1.w);
            *(ushort8v*)(xb + i) = o;
        }
        unsigned int w0 = __builtin_amdgcn_cvt_pk_fp8_f32(v0.x, v0.y, 0, 0);
        w0 = __builtin_amdgcn_cvt_pk_fp8_f32(v0.z, v0.w, w0, 1);
        unsigned int w1 = __builtin_amdgcn_cvt_pk_fp8_f32(v1.x, v1.y, 0, 0);
        w1 = __builtin_amdgcn_cvt_pk_fp8_f32(v1.z, v1.w, w1, 1);
        *(uint2*)(xq + i) = make_uint2(w0, w1);
    } else {
        int pb = b - HIST_BLOCKS - CONV_BLOCKS;
        int g = pb >> 8, n = pb & 255;
        const float* Wr = (g == 2) ? Wr2 : Wr1;
        const float* Wo = (g == 2) ? Wo2 : Wo1;
        const float* br = (g == 2) ? br2 : br1;
        int ka = (g == 1) ? 1 : 0;
        int kb = (g == 1) ? 4 : 2;
        for (int c = 0; c < 3; ++c) {
            int k = c * 256 + threadIdx.x;
            float v;
            if (k < 256)      v = Wr[(size_t)ka * 65536 + k * 256 + n];
            else if (k < 512) v = Wr[(size_t)kb * 65536 + (k - 256) * 256 + n];
            else              v = Wo[(size_t)ka * 65536 + (k - 512) * 256 + n] +
                                  Wo[(size_t)kb * 65536 + (k - 512) * 256 + n];
            BT[(size_t)g * 768 * 256 + (size_t)n * 768 + k] = f2bf(v);
        }
        if (n == 0) biascat[g * DIM + threadIdx.x] =
            br[ka * DIM + threadIdx.x] + br[kb * DIM + threadIdx.x];
    }
}

// ---------------------------------------------------------------------------
// Phase A: bin edges bucket-major. Pairs are PACKED to 4B: (src<<15)|dst
// (both < 32768). Halves pairs HBM traffic and the LDS staging buffer.
// ---------------------------------------------------------------------------
__global__ __launch_bounds__(256) void binA_scatter_kernel(const int* __restrict__ edges,
                                                           const int* __restrict__ part,
                                                           unsigned int* __restrict__ pairs) {
    int s = blockIdx.y, a0 = blockIdx.x;
    int k = slot_to_rel(s);
    const int* P = part + (size_t)s * ABLK * NBKT;
    __shared__ int tot[NBKT], pre[NBKT], bstart[NBKT];
    __shared__ int scn[NBKT], cur[NBKT], gb[NBKT];
    __shared__ unsigned int st[ACH];               // 16 KB packed
    if (threadIdx.x < NBKT) {
        int t = threadIdx.x, s_tot = 0, s_pre = 0;
        for (int a = 0; a < ABLK; ++a) {
            int v = P[a * NBKT + t];
            s_tot += v; if (a < a0) s_pre += v;
        }
        tot[t] = s_tot; pre[t] = s_pre;
    }
    __syncthreads();
    if (threadIdx.x == 0) {
        int run = 0;
        for (int b = 0; b < NBKT; ++b) { bstart[b] = run; run += tot[b]; }
        run = 0;
        for (int b = 0; b < NBKT; ++b) { scn[b] = run; run += P[a0 * NBKT + b]; }
    }
    __syncthreads();
    if (threadIdx.x < NBKT) {
        int t = threadIdx.x;
        cur[t] = scn[t];
        gb[t] = bstart[t] + pre[t] - scn[t];
    }
    __syncthreads();
    int e0 = a0 * ACH;
    #pragma unroll
    for (int j = 0; j < 16; ++j) {
        int e = e0 + j * 256 + threadIdx.x;
        if (e < NE) {
            unsigned int src = edges[k * 2 * NE + e];
            unsigned int dst = edges[k * 2 * NE + NE + e];
            int slot = atomicAdd(&cur[dst >> 8], 1);
            st[slot] = (src << 15) | dst;
        }
    }
    __syncthreads();
    int nthis = NE - e0; if (nthis > ACH) nthis = ACH;
    for (int i = threadIdx.x; i < nthis; i += 256) {
        unsigned int p = st[i];
        pairs[(size_t)s * NE + gb[(p & 32767u) >> 8] + i] = p;
    }
}

// ---------------------------------------------------------------------------
// Phase B: per (bucket, slot) — packed pairs loaded into LDS ONCE (stgIn),
// counted + scattered from LDS (no second global read), coalesced esorted
// write. LDS ~51 KB -> 3 blocks/CU.
// ---------------------------------------------------------------------------
__global__ __launch_bounds__(256) void binB_kernel(const unsigned int* __restrict__ pairs,
                                                   const int* __restrict__ part,
                                                   int* __restrict__ row_start,
                                                   int* __restrict__ esorted) {
    int s = blockIdx.y, b = blockIdx.x;
    const int* P = part + (size_t)s * ABLK * NBKT;
    __shared__ int tot[NBKT], bstartS[NBKT + 1];
    if (threadIdx.x < NBKT) {
        int t = threadIdx.x, s_tot = 0;
        for (int a = 0; a < ABLK; ++a) s_tot += P[a * NBKT + t];
        tot[t] = s_tot;
    }
    __syncthreads();
    if (threadIdx.x == 0) {
        int run = 0;
        for (int j = 0; j < NBKT; ++j) { bstartS[j] = run; run += tot[j]; }
        bstartS[NBKT] = run;
    }
    __syncthreads();
    int base = bstartS[b], end = bstartS[b + 1];
    int n = end - base;
    int row0 = b * BROWS;
    int nrows = NN - row0; if (nrows > BROWS) nrows = BROWS;

    __shared__ int rcnt[BROWS];
    __shared__ int rcur[BROWS];
    __shared__ unsigned int stgIn[STAGE_CAP];      // 24 KB
    __shared__ int stg[STAGE_CAP];                 // 24 KB
    __shared__ int w4[4];
    rcnt[threadIdx.x] = 0;
    __syncthreads();
    if (n <= STAGE_CAP) {
        for (int i = threadIdx.x; i < n; i += 256) {
            unsigned int p = pairs[(size_t)s * NE + base + i];
            stgIn[i] = p;
            atomicAdd(&rcnt[p & 255u], 1);
        }
    } else {
        for (int i = threadIdx.x; i < n; i += 256)
            atomicAdd(&rcnt[pairs[(size_t)s * NE + base + i] & 255u], 1);
    }
    __syncthreads();
    int lane = threadIdx.x & 63, w = threadIdx.x >> 6;
    int v = rcnt[threadIdx.x];
    int x = v;
    #pragma unroll
    for (int off = 1; off < 64; off <<= 1) {
        int t = __shfl_up(x, off, 64);
        if (lane >= off) x += t;
    }
    if (lane == 63) w4[w] = x;
    __syncthreads();
    int woff = 0;
    for (int j = 0; j < w; ++j) woff += w4[j];
    int excl = x - v + woff;
    if (threadIdx.x < nrows) row_start[s * NP1 + row0 + threadIdx.x] = base + excl;
    if (b == NBKT - 1 && threadIdx.x == 0) row_start[s * NP1 + NN] = end;
    rcur[threadIdx.x] = excl;
    __syncthreads();

    if (n <= STAGE_CAP) {
        for (int i = threadIdx.x; i < n; i += 256) {
            unsigned int p = stgIn[i];
            int pos = atomicAdd(&rcur[p & 255u], 1);
            stg[pos] = (int)(p >> 15);
        }
        __syncthreads();
        for (int i = threadIdx.x; i < n; i += 256)
            esorted[(size_t)s * NE + base + i] = stg[i];
    } else {  // pathological fallback
        for (int i = threadIdx.x; i < n; i += 256) {
            unsigned int p = pairs[(size_t)s * NE + base + i];
            int pos = atomicAdd(&rcur[p & 255u], 1);
            esorted[(size_t)s * NE + base + pos] = (int)(p >> 15);
        }
    }
}

// ---------------------------------------------------------------------------
// fp8 aggregation (R6 quad variant RESTORED — octet regressed in R7: doubled
// accumulator VGPRs without adding gather MLP). QUAD (16 lanes) per dst row,
// 4 rows per wave, 16 rows per block; lane owns 16 dims -> no cross-lane
// reduction. 4-edge unroll with next-iteration index prefetch. XCD swizzle:
// relation in LOW bits of blockIdx.x.
// ---------------------------------------------------------------------------
__device__ __forceinline__ void acc_row16(float2v* acc2, uint4 raw) {
    float2v f;
    f = __builtin_amdgcn_cvt_pk_f32_fp8(raw.x, 0); acc2[0] += f;
    f = __builtin_amdgcn_cvt_pk_f32_fp8(raw.x, 1); acc2[1] += f;
    f = __builtin_amdgcn_cvt_pk_f32_fp8(raw.y, 0); acc2[2] += f;
    f = __builtin_amdgcn_cvt_pk_f32_fp8(raw.y, 1); acc2[3] += f;
    f = __builtin_amdgcn_cvt_pk_f32_fp8(raw.z, 0); acc2[4] += f;
    f = __builtin_amdgcn_cvt_pk_f32_fp8(raw.z, 1); acc2[5] += f;
    f = __builtin_amdgcn_cvt_pk_f32_fp8(raw.w, 0); acc2[6] += f;
    f = __builtin_amdgcn_cvt_pk_f32_fp8(raw.w, 1); acc2[7] += f;
}

__device__ __forceinline__ void agg_row_quad(const unsigned char* __restrict__ feat,
                                             int b, int e, int c,
                                             const int* __restrict__ es,
                                             unsigned short* __restrict__ outp) {
    float2v acc2[8] = {};
    unsigned coff = (unsigned)c << 4;
    int i = b;
    int s0 = 0, s1 = 0, s2 = 0, s3 = 0;
    if (i + 3 < e) { s0 = es[i]; s1 = es[i + 1]; s2 = es[i + 2]; s3 = es[i + 3]; }
    while (i + 3 < e) {
        uint4 r0 = *(const uint4*)(feat + (((unsigned)s0 << 8) | coff));
        uint4 r1 = *(const uint4*)(feat + (((unsigned)s1 << 8) | coff));
        uint4 r2 = *(const uint4*)(feat + (((unsigned)s2 << 8) | coff));
        uint4 r3 = *(const uint4*)(feat + (((unsigned)s3 << 8) | coff));
        i += 4;
        if (i + 3 < e) { s0 = es[i]; s1 = es[i + 1]; s2 = es[i + 2]; s3 = es[i + 3]; }
        acc_row16(acc2, r0);
        acc_row16(acc2, r1);
        acc_row16(acc2, r2);
        acc_row16(acc2, r3);
    }
    for (; i < e; ++i) {
        int sl = es[i];
        uint4 r = *(const uint4*)(feat + (((unsigned)sl << 8) | coff));
        acc_row16(acc2, r);
    }
    ushort8v o0, o1;
    #pragma unroll
    for (int j = 0; j < 4; ++j) {
        o0[2 * j] = f2bf(acc2[j].x);     o0[2 * j + 1] = f2bf(acc2[j].y);
        o1[2 * j] = f2bf(acc2[4 + j].x); o1[2 * j + 1] = f2bf(acc2[4 + j].y);
    }
    *(ushort8v*)(outp) = o0;
    *(ushort8v*)(outp + 8) = o1;
}

__global__ __launch_bounds__(256) void aggregate_l1_kernel(const unsigned char* __restrict__ xq,
                                                           const int* __restrict__ row_start,
                                                           const int* __restrict__ esorted,
                                                           unsigned short* __restrict__ aggbase) {
    int bl = blockIdx.x;
    int s = bl & 3;                                // relation in low bits -> XCD pinning
    int rowblk = bl >> 2;                          // 16 rows per block
    int srct = (s == 2) ? 1 : ((s == 3) ? 2 : 0);
    const unsigned char* feat = xq + (size_t)srct * NN * DIM;
    const int* rs = row_start + s * NP1;
    const int* es = esorted + s * NE;
    unsigned short* out = aggbase + (size_t)s * NN * DIM;
    int w = threadIdx.x >> 6, lane = threadIdx.x & 63;
    int q = lane >> 4, c = lane & 15;
    int row = rowblk * 16 + w * 4 + q;             // 20000 % 16 == 0: no bounds check
    agg_row_quad(feat, rs[row], rs[row + 1], c, es,
                 out + (size_t)row * DIM + c * 16);
}

__global__ __launch_bounds__(256) void aggregate_l2_kernel(const unsigned char* __restrict__ h0q,
                                                           const unsigned char* __restrict__ h1q,
                                                           const int* __restrict__ row_start,
                                                           const int* __restrict__ esorted,
                                                           unsigned short* __restrict__ aggbase) {
    int bl = blockIdx.x;
    int qsel = bl & 1;                             // slot in low bit -> XCD pinning
    int rowblk = bl >> 1;
    int slot = qsel ? 2 : 0;
    const unsigned char* feat = qsel ? h1q : h0q;
    const int* rs = row_start + slot * NP1;
    const int* es = esorted + slot * NE;
    unsigned short* out = aggbase + (size_t)slot * NN * DIM;
    int w = threadIdx.x >> 6, lane = threadIdx.x & 63;
    int q = lane >> 4, c = lane & 15;
    int row = rowblk * 16 + w * 4 + q;
    agg_row_quad(feat, rs[row], rs[row + 1], c, es,
                 out + (size_t)row * DIM + c * 16);
}

// ---------------------------------------------------------------------------
// MFMA bf16 GEMM (layer 1) — R4 template (best measured). T2 swizzle (128B
// rows, slot ^ (row&7), pre-swizzled global src, linear LDS dest) + 2-phase
// raw-barrier pipeline with separate __shared__ arrays.
// ---------------------------------------------------------------------------
struct GemmArgs {
    const unsigned short* A0[2];
    const unsigned short* A1[2];
    const unsigned short* A2[2];
    const unsigned short* BT[2];
    const float* bias[2];
    unsigned short* Cb[2];   // bf16 out
    unsigned char* Cq[2];    // fp8 shadow out
    int relu;
    int M;
};

#define PIPE_BAR() asm volatile("s_waitcnt vmcnt(0)\n\ts_barrier" ::: "memory")

__global__ __launch_bounds__(256) void gemm_mfma_lds_kernel(GemmArgs ga) {
    __shared__ unsigned short As0[64 * 64];     // 8 KB
    __shared__ unsigned short As1[64 * 64];     // 8 KB
    __shared__ unsigned short Bs0[128 * 64];    // 16 KB
    __shared__ unsigned short Bs1[128 * 64];    // 16 KB
    int z = blockIdx.z;
    const unsigned short* Asrc[3] = {ga.A0[z], ga.A1[z], ga.A2[z]};
    const unsigned short* BT = ga.BT[z];
    int M = ga.M;

    int tid = threadIdx.x;
    int wave = tid >> 6, lane = tid & 63;
    int wc = wave;                                 // 4 col-groups of 32
    int row0 = blockIdx.x * 64;
    int col0 = blockIdx.y * 128;
    int q = lane >> 4, r = lane & 15;

    // Staging geometry: 8 lanes cover one 128B row; 16B slot XOR (row&7).
    int lrow = tid >> 3;                           // 0..31 (row within 32-row chunk)
    int gswz = (tid & 7) ^ (lrow & 7);             // swizzled global 16B slot
    int ldsbase = (tid & ~63) * 8;                 // halfwords, wave-uniform

    int ra0 = row0 + lrow;      if (ra0 > M - 1) ra0 = M - 1;
    int ra1 = row0 + 32 + lrow; if (ra1 > M - 1) ra1 = M - 1;
    size_t aoff0 = (size_t)ra0 * DIM + gswz * 8;
    size_t aoff1 = (size_t)ra1 * DIM + gswz * 8;
    size_t boff0 = (size_t)(col0 + lrow)      * 768 + gswz * 8;
    size_t boff1 = (size_t)(col0 + 32 + lrow) * 768 + gswz * 8;
    size_t boff2 = (size_t)(col0 + 64 + lrow) * 768 + gswz * 8;
    size_t boff3 = (size_t)(col0 + 96 + lrow) * 768 + gswz * 8;

    auto STAGE = [&](int bf, int t) {
        unsigned short* As = bf ? As1 : As0;       // constant bf -> folds
        unsigned short* Bs = bf ? Bs1 : Bs0;
        int seg = t >> 2;
        size_t kl = (size_t)(t & 3) * 64;          // k offset within A (DIM=256)
        size_t kb = (size_t)t * 64;                // k offset within BT (768)
        const unsigned short* Ap = Asrc[seg];
        __builtin_amdgcn_global_load_lds((gbl_vp*)(Ap + aoff0 + kl), (lds_vp*)&As[ldsbase],        16, 0, 0);
        __builtin_amdgcn_global_load_lds((gbl_vp*)(Ap + aoff1 + kl), (lds_vp*)&As[2048 + ldsbase], 16, 0, 0);
        __builtin_amdgcn_global_load_lds((gbl_vp*)(BT + boff0 + kb), (lds_vp*)&Bs[ldsbase],        16, 0, 0);
        __builtin_amdgcn_global_load_lds((gbl_vp*)(BT + boff1 + kb), (lds_vp*)&Bs[2048 + ldsbase], 16, 0, 0);
        __builtin_amdgcn_global_load_lds((gbl_vp*)(BT + boff2 + kb), (lds_vp*)&Bs[4096 + ldsbase], 16, 0, 0);
        __builtin_amdgcn_global_load_lds((gbl_vp*)(BT + boff3 + kb), (lds_vp*)&Bs[6144 + ldsbase], 16, 0, 0);
    };

    // Read-side swizzled slot offsets (halfwords), per-lane constants.
    int r7 = r & 7;
    int soff0 = ((0 * 4 + q) ^ r7) * 8;            // p = 0 (k 0..31)
    int soff1 = ((1 * 4 + q) ^ r7) * 8;            // p = 1 (k 32..63)

    float4v acc[4][2] = {};
    auto COMPUTE = [&](int bf) {
        const unsigned short* As = bf ? As1 : As0;
        const unsigned short* Bs = bf ? Bs1 : Bs0;
        #pragma unroll
        for (int p = 0; p < 2; ++p) {
            int so = p ? soff1 : soff0;
            short8v a[4], b[2];
            #pragma unroll
            for (int i = 0; i < 4; ++i)
                a[i] = *(const short8v*)&As[(i * 16 + r) * 64 + so];
            #pragma unroll
            for (int j = 0; j < 2; ++j)
                b[j] = *(const short8v*)&Bs[(wc * 32 + j * 16 + r) * 64 + so];
            #pragma unroll
            for (int i = 0; i < 4; ++i)
                #pragma unroll
                for (int j = 0; j < 2; ++j)
                    acc[i][j] = __builtin_amdgcn_mfma_f32_16x16x32_bf16(a[i], b[j], acc[i][j], 0, 0, 0);
        }
    };

    // 12 K-steps of BK=64 (K = 768), 2-phase double buffer.
    STAGE(0, 0);
    PIPE_BAR();
    #pragma unroll 1
    for (int t = 0; t < 10; t += 2) {
        STAGE(1, t + 1);
        COMPUTE(0);
        PIPE_BAR();
        STAGE(0, t + 2);
        COMPUTE(1);
        PIPE_BAR();
    }
    STAGE(1, 11);
    COMPUTE(0);             // t = 10
    PIPE_BAR();
    COMPUTE(1);             // t = 11

    // Epilogue. C/D layout: col = r, row = q*4 + e
    unsigned short* Cb = ga.Cb[z];
    unsigned char* Cq = ga.Cq[z];
    int colW0 = col0 + wc * 32;
    float bj[2];
    #pragma unroll
    for (int j = 0; j < 2; ++j) bj[j] = ga.bias[z][colW0 + j * 16 + r];
    #pragma unroll
    for (int i = 0; i < 4; ++i) {
        int rowb = row0 + i * 16 + q * 4;
        #pragma unroll
        for (int e = 0; e < 4; ++e) {
            int rowc = rowb + e;
            if (rowc < M) {
                #pragma unroll
                for (int j = 0; j < 2; ++j) {
                    int col = colW0 + j * 16 + r;
                    float v = acc[i][j][e] + bj[j];
                    if (ga.relu) v = fmaxf(v, 0.f);
                    Cb[(size_t)rowc * DIM + col] = f2bf(v);
                    Cq[(size_t)rowc * DIM + col] = f2fp8(v);
                }
            }
        }
    }
}

// ---------------------------------------------------------------------------
// Fused layer-2 GEMM + loss + MEAN: 64-row x 256-col tiles, 313 blocks.
// In-phase XOR swizzle (slot q ^ (r&3), pre-swizzled global src); mean fused
// via one atomicAdd per block. (Unchanged from R6.)
// ---------------------------------------------------------------------------
__global__ __launch_bounds__(256) void gemm_loss_kernel(const unsigned short* __restrict__ A0,
                                                        const unsigned short* __restrict__ A1,
                                                        const unsigned short* __restrict__ A2,
                                                        const unsigned short* __restrict__ BT,
                                                        const float* __restrict__ bias,
                                                        const int* __restrict__ y,
                                                        float* __restrict__ out) {
    __shared__ unsigned short Atile[2][64 * 32];    // 4 KB each
    __shared__ unsigned short Btile[2][256 * 32];   // 16 KB each
    __shared__ float redm[64][4];
    __shared__ float reds[64][4];
    __shared__ float ylog[64];
    __shared__ int ylds[64];
    const unsigned short* Asrc[3] = {A0, A1, A2};

    int tid = threadIdx.x;
    int wave = tid >> 6, lane = tid & 63;
    int wc = wave;                      // 4 waves = 4 col blocks of 64
    int row0 = blockIdx.x * 64;
    int q = lane >> 4, r = lane & 15;

    if (tid < 64) {
        int rowg = row0 + tid;
        ylds[tid] = (rowg < NN) ? y[rowg] : -1;
    }

    // Staging: 4 lanes per 64B row; 16B slot XOR (row&3) on the global src.
    int arow = tid >> 2;
    int aslot = (tid & 3) ^ (arow & 3);            // pre-swizzled 16B slot
    int acol = aslot * 8;
    int ra = row0 + arow; if (ra > NN - 1) ra = NN - 1;
    size_t aoff = (size_t)ra * DIM + acol;
    size_t boff0 = (size_t)(arow) * 768 + acol;    // row&3 == arow&3 for all
    size_t boff1 = (size_t)(64 + arow) * 768 + acol;
    size_t boff2 = (size_t)(128 + arow) * 768 + acol;
    size_t boff3 = (size_t)(192 + arow) * 768 + acol;
    int ldsA = (tid & ~63) * 8;
    int ldsB = (tid & ~63) * 8;

    // Read-side swizzled slot (halfword offset), per-lane constant.
    int soff = (q ^ (r & 3)) * 8;

    float4v acc[4][4] = {};
    #pragma unroll 1
    for (int seg = 0; seg < 3; ++seg) {
        const unsigned short* Ap = Asrc[seg];
        #pragma unroll 1
        for (int kt2 = 0; kt2 < 4; ++kt2) {
            int kl = kt2 * 64;
            int kb = seg * 256 + kl;
            #pragma unroll
            for (int p = 0; p < 2; ++p) {
                __builtin_amdgcn_global_load_lds((gbl_vp*)(Ap + aoff + kl + p * 32),
                                                 (lds_vp*)&Atile[p][ldsA], 16, 0, 0);
                __builtin_amdgcn_global_load_lds((gbl_vp*)(BT + boff0 + kb + p * 32),
                                                 (lds_vp*)&Btile[p][ldsB], 16, 0, 0);
                __builtin_amdgcn_global_load_lds((gbl_vp*)(BT + boff1 + kb + p * 32),
                                                 (lds_vp*)&Btile[p][2048 + ldsB], 16, 0, 0);
                __builtin_amdgcn_global_load_lds((gbl_vp*)(BT + boff2 + kb + p * 32),
                                                 (lds_vp*)&Btile[p][4096 + ldsB], 16, 0, 0);
                __builtin_amdgcn_global_load_lds((gbl_vp*)(BT + boff3 + kb + p * 32),
                                                 (lds_vp*)&Btile[p][6144 + ldsB], 16, 0, 0);
            }
            __syncthreads();
            #pragma unroll
            for (int p = 0; p < 2; ++p) {
                short8v a[4], b[4];
                #pragma unroll
                for (int i = 0; i < 4; ++i)
                    a[i] = *(const short8v*)&Atile[p][(i * 16 + r) * 32 + soff];
                #pragma unroll
                for (int j = 0; j < 4; ++j)
                    b[j] = *(const short8v*)&Btile[p][(wc * 64 + j * 16 + r) * 32 + soff];
                #pragma unroll
                for (int i = 0; i < 4; ++i)
                    #pragma unroll
                    for (int j = 0; j < 4; ++j)
                        acc[i][j] = __builtin_amdgcn_mfma_f32_16x16x32_bf16(a[i], b[j], acc[i][j], 0, 0, 0);
            }
            __syncthreads();
        }
    }

    float bj[4];
    #pragma unroll
    for (int j = 0; j < 4; ++j) bj[j] = bias[wc * 64 + j * 16 + r];
    #pragma unroll
    for (int i = 0; i < 4; ++i) {
        #pragma unroll
        for (int e = 0; e < 4; ++e) {
            int row_local = i * 16 + q * 4 + e;    // 0..63
            int ycls = ylds[row_local];
            float v[4];
            float m = -3.4e38f;
            #pragma unroll
            for (int j = 0; j < 4; ++j) {
                v[j] = acc[i][j][e] + bj[j];
                m = fmaxf(m, v[j]);
                int col = wc * 64 + j * 16 + r;
                if (col == ycls) ylog[row_local] = v[j];
            }
            #pragma unroll
            for (int off = 1; off < 16; off <<= 1) m = fmaxf(m, __shfl_xor(m, off, 64));
            float s = __expf(v[0] - m) + __expf(v[1] - m) + __expf(v[2] - m) + __expf(v[3] - m);
            #pragma unroll
            for (int off = 1; off < 16; off <<= 1) s += __shfl_xor(s, off, 64);
            if (r == 0) { redm[row_local][wc] = m; reds[row_local][wc] = s; }
        }
    }
    __syncthreads();
    if (tid < 64) {                                // wave 0 only (uniform per wave)
        float nllv = 0.f;
        int rowg = row0 + tid;
        if (rowg < NN) {
            float m0 = redm[tid][0], m1 = redm[tid][1], m2 = redm[tid][2], m3 = redm[tid][3];
            float mm = fmaxf(fmaxf(m0, m1), fmaxf(m2, m3));
            float ss = reds[tid][0] * __expf(m0 - mm) + reds[tid][1] * __expf(m1 - mm) +
                       reds[tid][2] * __expf(m2 - mm) + reds[tid][3] * __expf(m3 - mm);
            nllv = (mm + __logf(ss) - ylog[tid]) * (1.0f / NN);
        }
        #pragma unroll
        for (int off = 32; off; off >>= 1) nllv += __shfl_xor(nllv, off, 64);
        if (tid == 0) atomicAdd(out, nllv);
    }
}

// ---------------------------------------------------------------------------
extern "C" void kernel_launch(void* const* d_in, const int* in_sizes, int n_in,
                              void* d_out, int out_size, void* d_ws, size_t ws_size,
                              hipStream_t stream) {
    const float* x    = (const float*)d_in[0];
    const int*   edges= (const int*)d_in[1];
    const int*   y    = (const int*)d_in[2];
    const float* Wr1  = (const float*)d_in[3];
    const float* br1  = (const float*)d_in[4];
    const float* Wo1  = (const float*)d_in[5];
    const float* Wr2  = (const float*)d_in[6];
    const float* br2  = (const float*)d_in[7];
    const float* Wo2  = (const float*)d_in[8];
    float* out = (float*)d_out;

    char* ws = (char*)d_ws;
    size_t off = 0;
    auto alloc = [&](size_t bytes) {
        char* p = ws + off;
        off += (bytes + 511) & ~size_t(511);
        return p;
    };
    int*   part          = (int*)alloc(4 * (size_t)ABLK * NBKT * sizeof(int));
    unsigned int* pairs  = (unsigned int*)alloc(4 * (size_t)NE * sizeof(unsigned int));
    int*   rowstart      = (int*)alloc(4 * NP1 * sizeof(int));
    int*   esorted       = (int*)alloc(4 * (size_t)NE * sizeof(int));
    unsigned short* BT      = (unsigned short*)alloc(3 * 768 * (size_t)DIM * 2);
    float*          biascat = (float*)         alloc(3 * DIM * sizeof(float));
    unsigned short* xb      = (unsigned short*)alloc(2 * (size_t)NN * DIM * 2);
    unsigned char*  xq      = (unsigned char*) alloc(3 * (size_t)NN * DIM);
    unsigned short* agg     = (unsigned short*)alloc(4 * (size_t)NN * DIM * 2);
    unsigned short* h0      = (unsigned short*)alloc((size_t)NN * DIM * 2);
    unsigned short* h1      = (unsigned short*)alloc((size_t)NN * DIM * 2);
    unsigned char*  h0q     = (unsigned char*) alloc((size_t)NN * DIM);
    unsigned char*  h1q     = (unsigned char*) alloc((size_t)NN * DIM);
    (void)in_sizes; (void)n_in; (void)out_size; (void)ws_size;

    const size_t ND = (size_t)NN * DIM;

    // 1. Fused setup (bucket partial hist | x->bf16/fp8 | weights | out=0)
    setup_kernel<<<dim3(HIST_BLOCKS + CONV_BLOCKS + PREP_BLOCKS), 256, 0, stream>>>(
        x, edges, Wr1, br1, Wo1, Wr2, br2, Wo2, part, xb, xq, BT, biascat, out);

    // 2. Bucket sort: bin (packed 4B pairs) -> per-bucket LDS-staged scatter
    binA_scatter_kernel<<<dim3(ABLK, 4), 256, 0, stream>>>(edges, part, pairs);
    binB_kernel<<<dim3(NBKT, 4), 256, 0, stream>>>(pairs, part, rowstart, esorted);

    // 3. Layer-1 aggregation: quad-per-row, 16 rows/block, relation-per-XCD
    aggregate_l1_kernel<<<dim3((NN / 16) * 4), 256, 0, stream>>>(xq, rowstart, esorted, agg);

    // 4. Layer-1 MFMA GEMMs: 64x128 tiles, T2 swizzle + 2-phase pipe (R4 best)
    {
        GemmArgs ga;
        ga.A0[0] = agg + 0 * ND; ga.A1[0] = agg + 2 * ND; ga.A2[0] = xb + 0 * ND;
        ga.A0[1] = agg + 1 * ND; ga.A1[1] = agg + 3 * ND; ga.A2[1] = xb + 1 * ND;
        ga.BT[0] = BT + 0 * 768 * DIM; ga.BT[1] = BT + 1 * 768 * DIM;
        ga.bias[0] = biascat + 0 * DIM; ga.bias[1] = biascat + 1 * DIM;
        ga.Cb[0] = h0; ga.Cb[1] = h1;
        ga.Cq[0] = h0q; ga.Cq[1] = h1q;
        ga.relu = 1; ga.M = NN;
        gemm_mfma_lds_kernel<<<dim3((NN + 63) / 64, 2, 2), 256, 0, stream>>>(ga);
    }

    // 5. Layer-2 aggregation: quad-per-row, slot-per-XCD
    aggregate_l2_kernel<<<dim3((NN / 16) * 2), 256, 0, stream>>>(h0q, h1q, rowstart, esorted, agg);

    // 6. Fused layer-2 GEMM + softmax/nll + mean (atomic accumulate into out)
    gemm_loss_kernel<<<dim3((NN + 63) / 64), 256, 0, stream>>>(
        agg + 0 * ND, agg + 2 * ND, h0, BT + 2 * 768 * DIM, biascat + 2 * DIM, y, out);
}

// Round 9
// 265.561 us; speedup vs baseline: 1.0437x; 1.0061x over previous
//
#include <hip/hip_runtime.h>
#include <hip/hip_bf16.h>

#define NN 20000
#define NP1 20001
#define DIM 256
#define NE 320000

#define NBKT 79        // buckets of 256 dst rows (last bucket = 32 rows)
#define BROWS 256
#define ACH 4096       // edges per phase-A chunk
#define ABLK 79        // ceil(NE/ACH)
#define STAGE_CAP 6144

typedef __attribute__((ext_vector_type(8))) short short8v;   // 8 bf16 = 4 VGPRs
typedef __attribute__((ext_vector_type(4))) float float4v;
typedef __attribute__((ext_vector_type(2))) float float2v;
typedef __attribute__((ext_vector_type(8))) unsigned short ushort8v;

typedef __attribute__((address_space(3))) void lds_vp;
typedef const __attribute__((address_space(1))) void gbl_vp;

__device__ __forceinline__ unsigned short f2bf(float f) {
    unsigned int u = __float_as_uint(f);
    u += 0x7fffu + ((u >> 16) & 1u);          // round-to-nearest-even
    return (unsigned short)(u >> 16);
}
__device__ __forceinline__ unsigned char f2fp8(float f) {
    return (unsigned char)(__builtin_amdgcn_cvt_pk_fp8_f32(f, f, 0, 0) & 0xff);
}

__device__ __forceinline__ int slot_to_rel(int s) { return (s == 3) ? 4 : s; }

// ---------------------------------------------------------------------------
// Fused setup: bucket partial hist (atomic-free, private slices) |
// x -> {bf16, fp8} | weight prep | zero the loss accumulator
// ---------------------------------------------------------------------------
#define HIST_BLOCKS (4 * ABLK)             // 316
#define CONV_BLOCKS 7500                   // 3*NN*DIM / (256*8)
#define PREP_BLOCKS 768                    // 3 * 256

__global__ __launch_bounds__(256) void setup_kernel(const float* __restrict__ x,
                                                    const int* __restrict__ edges,
                                                    const float* __restrict__ Wr1,
                                                    const float* __restrict__ br1,
                                                    const float* __restrict__ Wo1,
                                                    const float* __restrict__ Wr2,
                                                    const float* __restrict__ br2,
                                                    const float* __restrict__ Wo2,
                                                    int* __restrict__ part,       // [4][ABLK][NBKT]
                                                    unsigned short* __restrict__ xb,
                                                    unsigned char* __restrict__ xq,
                                                    unsigned short* __restrict__ BT,
                                                    float* __restrict__ biascat,
                                                    float* __restrict__ out) {
    int b = blockIdx.x;
    if (b < HIST_BLOCKS) {
        if (b == 0 && threadIdx.x == 0) out[0] = 0.f;   // loss accumulator
        int s = b / ABLK, a = b - s * ABLK;
        int k = slot_to_rel(s);
        __shared__ int cnt[NBKT];
        for (int t = threadIdx.x; t < NBKT; t += 256) cnt[t] = 0;
        __syncthreads();
        int e0 = a * ACH;
        #pragma unroll
        for (int j = 0; j < 16; ++j) {
            int e = e0 + j * 256 + threadIdx.x;
            if (e < NE) atomicAdd(&cnt[edges[k * 2 * NE + NE + e] >> 8], 1);
        }
        __syncthreads();
        for (int t = threadIdx.x; t < NBKT; t += 256)
            part[(s * ABLK + a) * NBKT + t] = cnt[t];
    } else if (b < HIST_BLOCKS + CONV_BLOCKS) {
        size_t i = ((size_t)(b - HIST_BLOCKS) * 256 + threadIdx.x) * 8;
        float4 v0 = *(const float4*)(x + i);
        float4 v1 = *(const float4*)(x + i + 4);
        if (i < 2 * (size_t)NN * DIM) {    // bf16 roots only needed for types 0,1
            ushort8v o;
            o[0] = f2bf(v0.x); o[1] = f2bf(v0.y); o[2] = f2bf(v0.z); o[3] = f2bf(v0.w);
            o[4] = f2bf(v1.x); o[5] = f2bf(v1.y); o[6] = f2bf(v1.z); o[7] = f2bf(v1.w);
            *(ushort8v*)(xb + i) = o;
        }
        unsigned int w0 = __builtin_amdgcn_cvt_pk_fp8_f32(v0.x, v0.y, 0, 0);
        w0 = __builtin_amdgcn_cvt_pk_fp8_f32(v0.z, v0.w, w0, 1);
        unsigned int w1 = __builtin_amdgcn_cvt_pk_fp8_f32(v1.x, v1.y, 0, 0);
        w1 = __builtin_amdgcn_cvt_pk_fp8_f32(v1.z, v1.w, w1, 1);
        *(uint2*)(xq + i) = make_uint2(w0, w1);
    } else {
        int pb = b - HIST_BLOCKS - CONV_BLOCKS;
        int g = pb >> 8, n = pb & 255;
        const float* Wr = (g == 2) ? Wr2 : Wr1;
        const float* Wo = (g == 2) ? Wo2 : Wo1;
        const float* br = (g == 2) ? br2 : br1;
        int ka = (g == 1) ? 1 : 0;
        int kb = (g == 1) ? 4 : 2;
        for (int c = 0; c < 3; ++c) {
            int k = c * 256 + threadIdx.x;
            float v;
            if (k < 256)      v = Wr[(size_t)ka * 65536 + k * 256 + n];
            else if (k < 512) v = Wr[(size_t)kb * 65536 + (k - 256) * 256 + n];
            else              v = Wo[(size_t)ka * 65536 + (k - 512) * 256 + n] +
                                  Wo[(size_t)kb * 65536 + (k - 512) * 256 + n];
            BT[(size_t)g * 768 * 256 + (size_t)n * 768 + k] = f2bf(v);
        }
        if (n == 0) biascat[g * DIM + threadIdx.x] =
            br[ka * DIM + threadIdx.x] + br[kb * DIM + threadIdx.x];
    }
}

// ---------------------------------------------------------------------------
// Phase A: bin edges bucket-major. Pairs are PACKED to 4B: (src<<15)|dst
// (both < 32768). Halves pairs HBM traffic and the LDS staging buffer.
// ---------------------------------------------------------------------------
__global__ __launch_bounds__(256) void binA_scatter_kernel(const int* __restrict__ edges,
                                                           const int* __restrict__ part,
                                                           unsigned int* __restrict__ pairs) {
    int s = blockIdx.y, a0 = blockIdx.x;
    int k = slot_to_rel(s);
    const int* P = part + (size_t)s * ABLK * NBKT;
    __shared__ int tot[NBKT], pre[NBKT], bstart[NBKT];
    __shared__ int scn[NBKT], cur[NBKT], gb[NBKT];
    __shared__ unsigned int st[ACH];               // 16 KB packed
    if (threadIdx.x < NBKT) {
        int t = threadIdx.x, s_tot = 0, s_pre = 0;
        for (int a = 0; a < ABLK; ++a) {
            int v = P[a * NBKT + t];
            s_tot += v; if (a < a0) s_pre += v;
        }
        tot[t] = s_tot; pre[t] = s_pre;
    }
    __syncthreads();
    if (threadIdx.x == 0) {
        int run = 0;
        for (int b = 0; b < NBKT; ++b) { bstart[b] = run; run += tot[b]; }
        run = 0;
        for (int b = 0; b < NBKT; ++b) { scn[b] = run; run += P[a0 * NBKT + b]; }
    }
    __syncthreads();
    if (threadIdx.x < NBKT) {
        int t = threadIdx.x;
        cur[t] = scn[t];
        gb[t] = bstart[t] + pre[t] - scn[t];
    }
    __syncthreads();
    int e0 = a0 * ACH;
    #pragma unroll
    for (int j = 0; j < 16; ++j) {
        int e = e0 + j * 256 + threadIdx.x;
        if (e < NE) {
            unsigned int src = edges[k * 2 * NE + e];
            unsigned int dst = edges[k * 2 * NE + NE + e];
            int slot = atomicAdd(&cur[dst >> 8], 1);
            st[slot] = (src << 15) | dst;
        }
    }
    __syncthreads();
    int nthis = NE - e0; if (nthis > ACH) nthis = ACH;
    for (int i = threadIdx.x; i < nthis; i += 256) {
        unsigned int p = st[i];
        pairs[(size_t)s * NE + gb[(p & 32767u) >> 8] + i] = p;
    }
}

// ---------------------------------------------------------------------------
// Phase B: per (bucket, slot) — packed pairs loaded into LDS ONCE (stgIn),
// counted + scattered from LDS (no second global read), coalesced esorted
// write. LDS ~51 KB -> 3 blocks/CU.
// ---------------------------------------------------------------------------
__global__ __launch_bounds__(256) void binB_kernel(const unsigned int* __restrict__ pairs,
                                                   const int* __restrict__ part,
                                                   int* __restrict__ row_start,
                                                   int* __restrict__ esorted) {
    int s = blockIdx.y, b = blockIdx.x;
    const int* P = part + (size_t)s * ABLK * NBKT;
    __shared__ int tot[NBKT], bstartS[NBKT + 1];
    if (threadIdx.x < NBKT) {
        int t = threadIdx.x, s_tot = 0;
        for (int a = 0; a < ABLK; ++a) s_tot += P[a * NBKT + t];
        tot[t] = s_tot;
    }
    __syncthreads();
    if (threadIdx.x == 0) {
        int run = 0;
        for (int j = 0; j < NBKT; ++j) { bstartS[j] = run; run += tot[j]; }
        bstartS[NBKT] = run;
    }
    __syncthreads();
    int base = bstartS[b], end = bstartS[b + 1];
    int n = end - base;
    int row0 = b * BROWS;
    int nrows = NN - row0; if (nrows > BROWS) nrows = BROWS;

    __shared__ int rcnt[BROWS];
    __shared__ int rcur[BROWS];
    __shared__ unsigned int stgIn[STAGE_CAP];      // 24 KB
    __shared__ int stg[STAGE_CAP];                 // 24 KB
    __shared__ int w4[4];
    rcnt[threadIdx.x] = 0;
    __syncthreads();
    if (n <= STAGE_CAP) {
        for (int i = threadIdx.x; i < n; i += 256) {
            unsigned int p = pairs[(size_t)s * NE + base + i];
            stgIn[i] = p;
            atomicAdd(&rcnt[p & 255u], 1);
        }
    } else {
        for (int i = threadIdx.x; i < n; i += 256)
            atomicAdd(&rcnt[pairs[(size_t)s * NE + base + i] & 255u], 1);
    }
    __syncthreads();
    int lane = threadIdx.x & 63, w = threadIdx.x >> 6;
    int v = rcnt[threadIdx.x];
    int x = v;
    #pragma unroll
    for (int off = 1; off < 64; off <<= 1) {
        int t = __shfl_up(x, off, 64);
        if (lane >= off) x += t;
    }
    if (lane == 63) w4[w] = x;
    __syncthreads();
    int woff = 0;
    for (int j = 0; j < w; ++j) woff += w4[j];
    int excl = x - v + woff;
    if (threadIdx.x < nrows) row_start[s * NP1 + row0 + threadIdx.x] = base + excl;
    if (b == NBKT - 1 && threadIdx.x == 0) row_start[s * NP1 + NN] = end;
    rcur[threadIdx.x] = excl;
    __syncthreads();

    if (n <= STAGE_CAP) {
        for (int i = threadIdx.x; i < n; i += 256) {
            unsigned int p = stgIn[i];
            int pos = atomicAdd(&rcur[p & 255u], 1);
            stg[pos] = (int)(p >> 15);
        }
        __syncthreads();
        for (int i = threadIdx.x; i < n; i += 256)
            esorted[(size_t)s * NE + base + i] = stg[i];
    } else {  // pathological fallback
        for (int i = threadIdx.x; i < n; i += 256) {
            unsigned int p = pairs[(size_t)s * NE + base + i];
            int pos = atomicAdd(&rcur[p & 255u], 1);
            esorted[(size_t)s * NE + base + pos] = (int)(p >> 15);
        }
    }
}

// ---------------------------------------------------------------------------
// fp8 aggregation (quad variant — best measured). QUAD (16 lanes) per dst
// row, 4 rows per wave, 16 rows per block; lane owns 16 dims -> no
// cross-lane reduction. 4-edge unroll with next-iteration index prefetch.
// XCD swizzle: relation in LOW bits of blockIdx.x.
// ---------------------------------------------------------------------------
__device__ __forceinline__ void acc_row16(float2v* acc2, uint4 raw) {
    float2v f;
    f = __builtin_amdgcn_cvt_pk_f32_fp8(raw.x, 0); acc2[0] += f;
    f = __builtin_amdgcn_cvt_pk_f32_fp8(raw.x, 1); acc2[1] += f;
    f = __builtin_amdgcn_cvt_pk_f32_fp8(raw.y, 0); acc2[2] += f;
    f = __builtin_amdgcn_cvt_pk_f32_fp8(raw.y, 1); acc2[3] += f;
    f = __builtin_amdgcn_cvt_pk_f32_fp8(raw.z, 0); acc2[4] += f;
    f = __builtin_amdgcn_cvt_pk_f32_fp8(raw.z, 1); acc2[5] += f;
    f = __builtin_amdgcn_cvt_pk_f32_fp8(raw.w, 0); acc2[6] += f;
    f = __builtin_amdgcn_cvt_pk_f32_fp8(raw.w, 1); acc2[7] += f;
}

__device__ __forceinline__ void agg_row_quad(const unsigned char* __restrict__ feat,
                                             int b, int e, int c,
                                             const int* __restrict__ es,
                                             unsigned short* __restrict__ outp) {
    float2v acc2[8] = {};
    unsigned coff = (unsigned)c << 4;
    int i = b;
    int s0 = 0, s1 = 0, s2 = 0, s3 = 0;
    if (i + 3 < e) { s0 = es[i]; s1 = es[i + 1]; s2 = es[i + 2]; s3 = es[i + 3]; }
    while (i + 3 < e) {
        uint4 r0 = *(const uint4*)(feat + (((unsigned)s0 << 8) | coff));
        uint4 r1 = *(const uint4*)(feat + (((unsigned)s1 << 8) | coff));
        uint4 r2 = *(const uint4*)(feat + (((unsigned)s2 << 8) | coff));
        uint4 r3 = *(const uint4*)(feat + (((unsigned)s3 << 8) | coff));
        i += 4;
        if (i + 3 < e) { s0 = es[i]; s1 = es[i + 1]; s2 = es[i + 2]; s3 = es[i + 3]; }
        acc_row16(acc2, r0);
        acc_row16(acc2, r1);
        acc_row16(acc2, r2);
        acc_row16(acc2, r3);
    }
    for (; i < e; ++i) {
        int sl = es[i];
        uint4 r = *(const uint4*)(feat + (((unsigned)sl << 8) | coff));
        acc_row16(acc2, r);
    }
    ushort8v o0, o1;
    #pragma unroll
    for (int j = 0; j < 4; ++j) {
        o0[2 * j] = f2bf(acc2[j].x);     o0[2 * j + 1] = f2bf(acc2[j].y);
        o1[2 * j] = f2bf(acc2[4 + j].x); o1[2 * j + 1] = f2bf(acc2[4 + j].y);
    }
    *(ushort8v*)(outp) = o0;
    *(ushort8v*)(outp + 8) = o1;
}

__global__ __launch_bounds__(256) void aggregate_l1_kernel(const unsigned char* __restrict__ xq,
                                                           const int* __restrict__ row_start,
                                                           const int* __restrict__ esorted,
                                                           unsigned short* __restrict__ aggbase) {
    int bl = blockIdx.x;
    int s = bl & 3;                                // relation in low bits -> XCD pinning
    int rowblk = bl >> 2;                          // 16 rows per block
    int srct = (s == 2) ? 1 : ((s == 3) ? 2 : 0);
    const unsigned char* feat = xq + (size_t)srct * NN * DIM;
    const int* rs = row_start + s * NP1;
    const int* es = esorted + s * NE;
    unsigned short* out = aggbase + (size_t)s * NN * DIM;
    int w = threadIdx.x >> 6, lane = threadIdx.x & 63;
    int q = lane >> 4, c = lane & 15;
    int row = rowblk * 16 + w * 4 + q;             // 20000 % 16 == 0: no bounds check
    agg_row_quad(feat, rs[row], rs[row + 1], c, es,
                 out + (size_t)row * DIM + c * 16);
}

__global__ __launch_bounds__(256) void aggregate_l2_kernel(const unsigned char* __restrict__ h0q,
                                                           const unsigned char* __restrict__ h1q,
                                                           const int* __restrict__ row_start,
                                                           const int* __restrict__ esorted,
                                                           unsigned short* __restrict__ aggbase) {
    int bl = blockIdx.x;
    int qsel = bl & 1;                             // slot in low bit -> XCD pinning
    int rowblk = bl >> 1;
    int slot = qsel ? 2 : 0;
    const unsigned char* feat = qsel ? h1q : h0q;
    const int* rs = row_start + slot * NP1;
    const int* es = esorted + slot * NE;
    unsigned short* out = aggbase + (size_t)slot * NN * DIM;
    int w = threadIdx.x >> 6, lane = threadIdx.x & 63;
    int q = lane >> 4, c = lane & 15;
    int row = rowblk * 16 + w * 4 + q;
    agg_row_quad(feat, rs[row], rs[row + 1], c, es,
                 out + (size_t)row * DIM + c * 16);
}

// ---------------------------------------------------------------------------
// MFMA bf16 GEMM (layer 1), round-9: 64 rows x 256 cols (FULL N) per block.
//   - A is fetched ONCE (was twice with 2 col-blocks): FETCH 64 -> ~34 MB.
//   - MFMA-per-drain doubles (128/step/block vs 64): each vmcnt(0) drain is
//     amortized over 2x matrix-pipe work. Same proven PIPE_BAR 2-phase
//     template as R4/R8 (NOT a new sync structure), same T2 swizzle.
//   - h1 bf16 is dead output (gemm_loss reads h0 only): Cb[1] = nullptr
//     skips the z=1 bf16 store (-10 MB writes).
//   LDS 80 KB -> 2 blocks/CU; grid 313 x 2z = 626 blocks.
// ---------------------------------------------------------------------------
struct GemmArgs {
    const unsigned short* A0[2];
    const unsigned short* A1[2];
    const unsigned short* A2[2];
    const unsigned short* BT[2];
    const float* bias[2];
    unsigned short* Cb[2];   // bf16 out (nullptr = skip store)
    unsigned char* Cq[2];    // fp8 shadow out
    int relu;
    int M;
};

#define PIPE_BAR() asm volatile("s_waitcnt vmcnt(0)\n\ts_barrier" ::: "memory")

__global__ __launch_bounds__(256) void gemm_mfma_lds_kernel(GemmArgs ga) {
    __shared__ unsigned short As0[64 * 64];      // 8 KB
    __shared__ unsigned short As1[64 * 64];      // 8 KB
    __shared__ unsigned short Bs0[256 * 64];     // 32 KB
    __shared__ unsigned short Bs1[256 * 64];     // 32 KB
    int z = blockIdx.y;
    const unsigned short* Asrc[3] = {ga.A0[z], ga.A1[z], ga.A2[z]};
    const unsigned short* BT = ga.BT[z];
    int M = ga.M;

    int tid = threadIdx.x;
    int wave = tid >> 6, lane = tid & 63;
    int wc = wave;                                 // 4 col-groups of 64
    int row0 = blockIdx.x * 64;
    int q = lane >> 4, r = lane & 15;

    // Staging geometry: 8 lanes cover one 128B row; 16B slot XOR (row&7).
    int lrow = tid >> 3;                           // 0..31 (row within 32-row chunk)
    int gswz = (tid & 7) ^ (lrow & 7);             // swizzled global 16B slot
    int ldsbase = (tid & ~63) * 8;                 // halfwords, wave-uniform

    int ra0 = row0 + lrow;      if (ra0 > M - 1) ra0 = M - 1;
    int ra1 = row0 + 32 + lrow; if (ra1 > M - 1) ra1 = M - 1;
    size_t aoff0 = (size_t)ra0 * DIM + gswz * 8;
    size_t aoff1 = (size_t)ra1 * DIM + gswz * 8;
    size_t boff[8];
    #pragma unroll
    for (int kk = 0; kk < 8; ++kk)
        boff[kk] = (size_t)(kk * 32 + lrow) * 768 + gswz * 8;

    auto STAGE = [&](int bf, int t) {
        unsigned short* As = bf ? As1 : As0;       // constant bf -> folds
        unsigned short* Bs = bf ? Bs1 : Bs0;
        int seg = t >> 2;
        size_t kl = (size_t)(t & 3) * 64;          // k offset within A (DIM=256)
        size_t kb = (size_t)t * 64;                // k offset within BT (768)
        const unsigned short* Ap = Asrc[seg];
        __builtin_amdgcn_global_load_lds((gbl_vp*)(Ap + aoff0 + kl), (lds_vp*)&As[ldsbase],        16, 0, 0);
        __builtin_amdgcn_global_load_lds((gbl_vp*)(Ap + aoff1 + kl), (lds_vp*)&As[2048 + ldsbase], 16, 0, 0);
        #pragma unroll
        for (int kk = 0; kk < 8; ++kk)
            __builtin_amdgcn_global_load_lds((gbl_vp*)(BT + boff[kk] + kb),
                                             (lds_vp*)&Bs[kk * 2048 + ldsbase], 16, 0, 0);
    };

    // Read-side swizzled slot offsets (halfwords), per-lane constants.
    int r7 = r & 7;
    int soff0 = ((0 * 4 + q) ^ r7) * 8;            // p = 0 (k 0..31)
    int soff1 = ((1 * 4 + q) ^ r7) * 8;            // p = 1 (k 32..63)

    float4v acc[4][4] = {};
    auto COMPUTE = [&](int bf) {
        const unsigned short* As = bf ? As1 : As0;
        const unsigned short* Bs = bf ? Bs1 : Bs0;
        #pragma unroll
        for (int p = 0; p < 2; ++p) {
            int so = p ? soff1 : soff0;
            short8v a[4], b[4];
            #pragma unroll
            for (int i = 0; i < 4; ++i)
                a[i] = *(const short8v*)&As[(i * 16 + r) * 64 + so];
            #pragma unroll
            for (int j = 0; j < 4; ++j)
                b[j] = *(const short8v*)&Bs[(wc * 64 + j * 16 + r) * 64 + so];
            #pragma unroll
            for (int i = 0; i < 4; ++i)
                #pragma unroll
                for (int j = 0; j < 4; ++j)
                    acc[i][j] = __builtin_amdgcn_mfma_f32_16x16x32_bf16(a[i], b[j], acc[i][j], 0, 0, 0);
        }
    };

    // 12 K-steps of BK=64 (K = 768), 2-phase double buffer.
    STAGE(0, 0);
    PIPE_BAR();
    #pragma unroll 1
    for (int t = 0; t < 10; t += 2) {
        STAGE(1, t + 1);
        COMPUTE(0);
        PIPE_BAR();
        STAGE(0, t + 2);
        COMPUTE(1);
        PIPE_BAR();
    }
    STAGE(1, 11);
    COMPUTE(0);             // t = 10
    PIPE_BAR();
    COMPUTE(1);             // t = 11

    // Epilogue. C/D layout: col = r, row = q*4 + e
    unsigned short* Cb = ga.Cb[z];
    unsigned char* Cq = ga.Cq[z];
    int colW0 = wc * 64;
    float bj[4];
    #pragma unroll
    for (int j = 0; j < 4; ++j) bj[j] = ga.bias[z][colW0 + j * 16 + r];
    #pragma unroll
    for (int i = 0; i < 4; ++i) {
        int rowb = row0 + i * 16 + q * 4;
        #pragma unroll
        for (int e = 0; e < 4; ++e) {
            int rowc = rowb + e;
            if (rowc < M) {
                #pragma unroll
                for (int j = 0; j < 4; ++j) {
                    int col = colW0 + j * 16 + r;
                    float v = acc[i][j][e] + bj[j];
                    if (ga.relu) v = fmaxf(v, 0.f);
                    if (Cb) Cb[(size_t)rowc * DIM + col] = f2bf(v);
                    Cq[(size_t)rowc * DIM + col] = f2fp8(v);
                }
            }
        }
    }
}

// ---------------------------------------------------------------------------
// Fused layer-2 GEMM + loss + MEAN: 64-row x 256-col tiles, 313 blocks.
// In-phase XOR swizzle (slot q ^ (r&3), pre-swizzled global src); mean fused
// via one atomicAdd per block. (Unchanged from R8.)
// ---------------------------------------------------------------------------
__global__ __launch_bounds__(256) void gemm_loss_kernel(const unsigned short* __restrict__ A0,
                                                        const unsigned short* __restrict__ A1,
                                                        const unsigned short* __restrict__ A2,
                                                        const unsigned short* __restrict__ BT,
                                                        const float* __restrict__ bias,
                                                        const int* __restrict__ y,
                                                        float* __restrict__ out) {
    __shared__ unsigned short Atile[2][64 * 32];    // 4 KB each
    __shared__ unsigned short Btile[2][256 * 32];   // 16 KB each
    __shared__ float redm[64][4];
    __shared__ float reds[64][4];
    __shared__ float ylog[64];
    __shared__ int ylds[64];
    const unsigned short* Asrc[3] = {A0, A1, A2};

    int tid = threadIdx.x;
    int wave = tid >> 6, lane = tid & 63;
    int wc = wave;                      // 4 waves = 4 col blocks of 64
    int row0 = blockIdx.x * 64;
    int q = lane >> 4, r = lane & 15;

    if (tid < 64) {
        int rowg = row0 + tid;
        ylds[tid] = (rowg < NN) ? y[rowg] : -1;
    }

    // Staging: 4 lanes per 64B row; 16B slot XOR (row&3) on the global src.
    int arow = tid >> 2;
    int aslot = (tid & 3) ^ (arow & 3);            // pre-swizzled 16B slot
    int acol = aslot * 8;
    int ra = row0 + arow; if (ra > NN - 1) ra = NN - 1;
    size_t aoff = (size_t)ra * DIM + acol;
    size_t boff0 = (size_t)(arow) * 768 + acol;    // row&3 == arow&3 for all
    size_t boff1 = (size_t)(64 + arow) * 768 + acol;
    size_t boff2 = (size_t)(128 + arow) * 768 + acol;
    size_t boff3 = (size_t)(192 + arow) * 768 + acol;
    int ldsA = (tid & ~63) * 8;
    int ldsB = (tid & ~63) * 8;

    // Read-side swizzled slot (halfword offset), per-lane constant.
    int soff = (q ^ (r & 3)) * 8;

    float4v acc[4][4] = {};
    #pragma unroll 1
    for (int seg = 0; seg < 3; ++seg) {
        const unsigned short* Ap = Asrc[seg];
        #pragma unroll 1
        for (int kt2 = 0; kt2 < 4; ++kt2) {
            int kl = kt2 * 64;
            int kb = seg * 256 + kl;
            #pragma unroll
            for (int p = 0; p < 2; ++p) {
                __builtin_amdgcn_global_load_lds((gbl_vp*)(Ap + aoff + kl + p * 32),
                                                 (lds_vp*)&Atile[p][ldsA], 16, 0, 0);
                __builtin_amdgcn_global_load_lds((gbl_vp*)(BT + boff0 + kb + p * 32),
                                                 (lds_vp*)&Btile[p][ldsB], 16, 0, 0);
                __builtin_amdgcn_global_load_lds((gbl_vp*)(BT + boff1 + kb + p * 32),
                                                 (lds_vp*)&Btile[p][2048 + ldsB], 16, 0, 0);
                __builtin_amdgcn_global_load_lds((gbl_vp*)(BT + boff2 + kb + p * 32),
                                                 (lds_vp*)&Btile[p][4096 + ldsB], 16, 0, 0);
                __builtin_amdgcn_global_load_lds((gbl_vp*)(BT + boff3 + kb + p * 32),
                                                 (lds_vp*)&Btile[p][6144 + ldsB], 16, 0, 0);
            }
            __syncthreads();
            #pragma unroll
            for (int p = 0; p < 2; ++p) {
                short8v a[4], b[4];
                #pragma unroll
                for (int i = 0; i < 4; ++i)
                    a[i] = *(const short8v*)&Atile[p][(i * 16 + r) * 32 + soff];
                #pragma unroll
                for (int j = 0; j < 4; ++j)
                    b[j] = *(const short8v*)&Btile[p][(wc * 64 + j * 16 + r) * 32 + soff];
                #pragma unroll
                for (int i = 0; i < 4; ++i)
                    #pragma unroll
                    for (int j = 0; j < 4; ++j)
                        acc[i][j] = __builtin_amdgcn_mfma_f32_16x16x32_bf16(a[i], b[j], acc[i][j], 0, 0, 0);
            }
            __syncthreads();
        }
    }

    float bj[4];
    #pragma unroll
    for (int j = 0; j < 4; ++j) bj[j] = bias[wc * 64 + j * 16 + r];
    #pragma unroll
    for (int i = 0; i < 4; ++i) {
        #pragma unroll
        for (int e = 0; e < 4; ++e) {
            int row_local = i * 16 + q * 4 + e;    // 0..63
            int ycls = ylds[row_local];
            float v[4];
            float m = -3.4e38f;
            #pragma unroll
            for (int j = 0; j < 4; ++j) {
                v[j] = acc[i][j][e] + bj[j];
                m = fmaxf(m, v[j]);
                int col = wc * 64 + j * 16 + r;
                if (col == ycls) ylog[row_local] = v[j];
            }
            #pragma unroll
            for (int off = 1; off < 16; off <<= 1) m = fmaxf(m, __shfl_xor(m, off, 64));
            float s = __expf(v[0] - m) + __expf(v[1] - m) + __expf(v[2] - m) + __expf(v[3] - m);
            #pragma unroll
            for (int off = 1; off < 16; off <<= 1) s += __shfl_xor(s, off, 64);
            if (r == 0) { redm[row_local][wc] = m; reds[row_local][wc] = s; }
        }
    }
    __syncthreads();
    if (tid < 64) {                                // wave 0 only (uniform per wave)
        float nllv = 0.f;
        int rowg = row0 + tid;
        if (rowg < NN) {
            float m0 = redm[tid][0], m1 = redm[tid][1], m2 = redm[tid][2], m3 = redm[tid][3];
            float mm = fmaxf(fmaxf(m0, m1), fmaxf(m2, m3));
            float ss = reds[tid][0] * __expf(m0 - mm) + reds[tid][1] * __expf(m1 - mm) +
                       reds[tid][2] * __expf(m2 - mm) + reds[tid][3] * __expf(m3 - mm);
            nllv = (mm + __logf(ss) - ylog[tid]) * (1.0f / NN);
        }
        #pragma unroll
        for (int off = 32; off; off >>= 1) nllv += __shfl_xor(nllv, off, 64);
        if (tid == 0) atomicAdd(out, nllv);
    }
}

// ---------------------------------------------------------------------------
extern "C" void kernel_launch(void* const* d_in, const int* in_sizes, int n_in,
                              void* d_out, int out_size, void* d_ws, size_t ws_size,
                              hipStream_t stream) {
    const float* x    = (const float*)d_in[0];
    const int*   edges= (const int*)d_in[1];
    const int*   y    = (const int*)d_in[2];
    const float* Wr1  = (const float*)d_in[3];
    const float* br1  = (const float*)d_in[4];
    const float* Wo1  = (const float*)d_in[5];
    const float* Wr2  = (const float*)d_in[6];
    const float* br2  = (const float*)d_in[7];
    const float* Wo2  = (const float*)d_in[8];
    float* out = (float*)d_out;

    char* ws = (char*)d_ws;
    size_t off = 0;
    auto alloc = [&](size_t bytes) {
        char* p = ws + off;
        off += (bytes + 511) & ~size_t(511);
        return p;
    };
    int*   part          = (int*)alloc(4 * (size_t)ABLK * NBKT * sizeof(int));
    unsigned int* pairs  = (unsigned int*)alloc(4 * (size_t)NE * sizeof(unsigned int));
    int*   rowstart      = (int*)alloc(4 * NP1 * sizeof(int));
    int*   esorted       = (int*)alloc(4 * (size_t)NE * sizeof(int));
    unsigned short* BT      = (unsigned short*)alloc(3 * 768 * (size_t)DIM * 2);
    float*          biascat = (float*)         alloc(3 * DIM * sizeof(float));
    unsigned short* xb      = (unsigned short*)alloc(2 * (size_t)NN * DIM * 2);
    unsigned char*  xq      = (unsigned char*) alloc(3 * (size_t)NN * DIM);
    unsigned short* agg     = (unsigned short*)alloc(4 * (size_t)NN * DIM * 2);
    unsigned short* h0      = (unsigned short*)alloc((size_t)NN * DIM * 2);
    unsigned char*  h0q     = (unsigned char*) alloc((size_t)NN * DIM);
    unsigned char*  h1q     = (unsigned char*) alloc((size_t)NN * DIM);
    (void)in_sizes; (void)n_in; (void)out_size; (void)ws_size;

    const size_t ND = (size_t)NN * DIM;

    // 1. Fused setup (bucket partial hist | x->bf16/fp8 | weights | out=0)
    setup_kernel<<<dim3(HIST_BLOCKS + CONV_BLOCKS + PREP_BLOCKS), 256, 0, stream>>>(
        x, edges, Wr1, br1, Wo1, Wr2, br2, Wo2, part, xb, xq, BT, biascat, out);

    // 2. Bucket sort: bin (packed 4B pairs) -> per-bucket LDS-staged scatter
    binA_scatter_kernel<<<dim3(ABLK, 4), 256, 0, stream>>>(edges, part, pairs);
    binB_kernel<<<dim3(NBKT, 4), 256, 0, stream>>>(pairs, part, rowstart, esorted);

    // 3. Layer-1 aggregation: quad-per-row, 16 rows/block, relation-per-XCD
    aggregate_l1_kernel<<<dim3((NN / 16) * 4), 256, 0, stream>>>(xq, rowstart, esorted, agg);

    // 4. Layer-1 MFMA GEMMs: 64x256 tiles (full N, A read once), z in grid.y;
    //    h1 bf16 store skipped (dead output).
    {
        GemmArgs ga;
        ga.A0[0] = agg + 0 * ND; ga.A1[0] = agg + 2 * ND; ga.A2[0] = xb + 0 * ND;
        ga.A0[1] = agg + 1 * ND; ga.A1[1] = agg + 3 * ND; ga.A2[1] = xb + 1 * ND;
        ga.BT[0] = BT + 0 * 768 * DIM; ga.BT[1] = BT + 1 * 768 * DIM;
        ga.bias[0] = biascat + 0 * DIM; ga.bias[1] = biascat + 1 * DIM;
        ga.Cb[0] = h0; ga.Cb[1] = nullptr;
        ga.Cq[0] = h0q; ga.Cq[1] = h1q;
        ga.relu = 1; ga.M = NN;
        gemm_mfma_lds_kernel<<<dim3((NN + 63) / 64, 2), 256, 0, stream>>>(ga);
    }

    // 5. Layer-2 aggregation: quad-per-row, slot-per-XCD
    aggregate_l2_kernel<<<dim3((NN / 16) * 2), 256, 0, stream>>>(h0q, h1q, rowstart, esorted, agg);

    // 6. Fused layer-2 GEMM + softmax/nll + mean (atomic accumulate into out)
    gemm_loss_kernel<<<dim3((NN + 63) / 64), 256, 0, stream>>>(
        agg + 0 * ND, agg + 2 * ND, h0, BT + 2 * 768 * DIM, biascat + 2 * DIM, y, out);
}